// Round 1
// baseline (913.336 us; speedup 1.0000x reference)
//
#include <hip/hip_runtime.h>
#include <hip/hip_bf16.h>

// ---------------------------------------------------------------------------
// EncoderBlock: pre-LN transformer block, B=2 S=1024 D=1024 H=16 DK=64 DFC=4096
// Strategy (round 1, correctness-first):
//   fp32 inputs -> bf16 internal compute via mfma_f32_16x16x32_bf16.
//   - ln1 -> bf16
//   - q,k,v = 3x gemm_bt (y = x @ W^T; W rows contiguous in k -> "B^T" GEMM)
//   - v transposed to (B,H,DK,S) so PV fragments are 16B contiguous loads
//   - fused attention: 1 wave / 16 q-rows, scores in 64KB LDS, 2-pass softmax
//   - o-proj + residual (fp32), ln2, fc1+bias+relu, fc2+bias+residual -> d_out
// MFMA layouts (verified in guide): A[m=lane&15][k=(lane>>4)*8+j],
//   B[k=(lane>>4)*8+j][n=lane&15], C/D row=(lane>>4)*4+reg, col=lane&15.
// ---------------------------------------------------------------------------

typedef __bf16 bf16;
typedef __attribute__((ext_vector_type(8))) __bf16 bf16x8;
typedef __attribute__((ext_vector_type(4))) __bf16 bf16x4;
typedef __attribute__((ext_vector_type(4))) float f32x4;

#define NTOK 2048   // B*S
#define DM   1024
#define DFC  4096

// ---------------- fp32 -> bf16 convert (vectorized) ----------------
__global__ __launch_bounds__(256) void f2b4_kernel(const float4* __restrict__ in,
                                                   bf16x4* __restrict__ out, int n4) {
    int i = blockIdx.x * 256 + threadIdx.x;
    if (i < n4) {
        float4 v = in[i];
        bf16x4 o;
        o[0] = (bf16)v.x; o[1] = (bf16)v.y; o[2] = (bf16)v.z; o[3] = (bf16)v.w;
        out[i] = o;
    }
}

// ---------------- LayerNorm (torch semantics: std ddof=1, /(std+eps)) -------
__global__ __launch_bounds__(256) void ln_kernel(const float* __restrict__ x,
                                                 const float* __restrict__ alpha,
                                                 const float* __restrict__ beta,
                                                 bf16* __restrict__ out) {
    int row = blockIdx.x;
    int t = threadIdx.x;                    // 256 threads, 4 elems each
    float4 v = reinterpret_cast<const float4*>(x + (size_t)row * DM)[t];
    float s  = v.x + v.y + v.z + v.w;
    float ss = v.x * v.x + v.y * v.y + v.z * v.z + v.w * v.w;
    __shared__ float red[8];
    int lane = t & 63, wv = t >> 6;
    #pragma unroll
    for (int o = 32; o > 0; o >>= 1) {
        s  += __shfl_down(s, o);
        ss += __shfl_down(ss, o);
    }
    if (lane == 0) { red[wv] = s; red[4 + wv] = ss; }
    __syncthreads();
    float S  = red[0] + red[1] + red[2] + red[3];
    float SS = red[4] + red[5] + red[6] + red[7];
    float mean = S * (1.0f / 1024.0f);
    float var  = (SS - S * mean) * (1.0f / 1023.0f);   // ddof=1
    var = var < 0.f ? 0.f : var;
    float inv = 1.0f / (sqrtf(var) + 1e-6f);           // /(std+eps)
    float4 a4 = reinterpret_cast<const float4*>(alpha)[t];
    float4 b4 = reinterpret_cast<const float4*>(beta)[t];
    bf16x4 o4;
    o4[0] = (bf16)(a4.x * (v.x - mean) * inv + b4.x);
    o4[1] = (bf16)(a4.y * (v.y - mean) * inv + b4.y);
    o4[2] = (bf16)(a4.z * (v.z - mean) * inv + b4.z);
    o4[3] = (bf16)(a4.w * (v.w - mean) * inv + b4.w);
    reinterpret_cast<bf16x4*>(out + (size_t)row * DM)[t] = o4;
}

// ---------------- GEMM: C[m][n] = sum_k A[m][k] * Bt[n][k] (+ epilogue) -----
// grid (N/64, M/64), block 256 = 4 waves; wave w: rows m0+16w..+15, cols n0..n0+63
// EPI: 0 = store bf16; 1 = relu(v+bias) bf16; 2 = v+bias+resid fp32; 3 = v+resid fp32
template <int EPI>
__global__ __launch_bounds__(256) void gemm_bt(const bf16* __restrict__ A,
                                               const bf16* __restrict__ Bt,
                                               void* __restrict__ outp,
                                               const float* __restrict__ bias,
                                               const float* __restrict__ resid,
                                               int M, int N, int K) {
    int lane = threadIdx.x & 63;
    int wave = threadIdx.x >> 6;
    int q = lane >> 4, r = lane & 15;
    int m0 = blockIdx.y * 64 + wave * 16;
    int n0 = blockIdx.x * 64;
    f32x4 acc[4] = {};
    const bf16* arow = A  + (size_t)(m0 + r) * K + q * 8;
    const bf16* brow = Bt + (size_t)(n0 + r) * K + q * 8;
    for (int k0 = 0; k0 < K; k0 += 32) {
        bf16x8 af = *reinterpret_cast<const bf16x8*>(arow + k0);
        #pragma unroll
        for (int t = 0; t < 4; ++t) {
            bf16x8 bfv = *reinterpret_cast<const bf16x8*>(brow + (size_t)t * 16 * K + k0);
            acc[t] = __builtin_amdgcn_mfma_f32_16x16x32_bf16(af, bfv, acc[t], 0, 0, 0);
        }
    }
    #pragma unroll
    for (int t = 0; t < 4; ++t) {
        #pragma unroll
        for (int i = 0; i < 4; ++i) {
            int mm = m0 + q * 4 + i;
            int nn = n0 + t * 16 + r;
            size_t idx = (size_t)mm * N + nn;
            float v = acc[t][i];
            if (EPI == 0) {
                ((bf16*)outp)[idx] = (bf16)v;
            } else if (EPI == 1) {
                v += bias[nn];
                ((bf16*)outp)[idx] = (bf16)(v > 0.f ? v : 0.f);
            } else if (EPI == 2) {
                ((float*)outp)[idx] = v + bias[nn] + resid[idx];
            } else {
                ((float*)outp)[idx] = v + resid[idx];
            }
        }
    }
}

// ---------------- V transpose: (B,S,H*DK) -> (B,H,DK,S) ---------------------
__global__ void transpose_v(const bf16* __restrict__ v, bf16* __restrict__ vt) {
    __shared__ bf16 tile[32][33];
    int bh = blockIdx.z;            // b*16+h
    int b = bh >> 4, h = bh & 15;
    int s0 = blockIdx.x * 32;
    int d0 = blockIdx.y * 32;
    int tx = threadIdx.x, ty = threadIdx.y;
    tile[ty][tx] = v[((size_t)(b * 1024 + s0 + ty)) * DM + h * 64 + d0 + tx];
    __syncthreads();
    vt[((size_t)(bh * 64 + d0 + ty)) * 1024 + s0 + tx] = tile[tx][ty];
}

// ---------------- fused attention: 1 wave, 16 q-rows, full 1024-key pass ----
__global__ __launch_bounds__(64) void attn_kernel(const bf16* __restrict__ Q,
                                                  const bf16* __restrict__ Kb,
                                                  const bf16* __restrict__ Vt,
                                                  const int* __restrict__ mask,
                                                  bf16* __restrict__ out) {
    __shared__ float sc[16][1024];   // exactly 64 KiB
    int lane = threadIdx.x;
    int q = lane >> 4, r = lane & 15;
    int idx = blockIdx.x;            // b*1024 + h*64 + qt
    int qt = idx & 63;
    int h  = (idx >> 6) & 15;
    int b  = idx >> 10;

    // Q fragments (held for all key tiles): rows qt*16+r, dk = q*8+j (+32)
    const bf16* qbase = Q + ((size_t)(b * 1024 + qt * 16 + r)) * DM + h * 64 + q * 8;
    bf16x8 qf0 = *reinterpret_cast<const bf16x8*>(qbase);
    bf16x8 qf1 = *reinterpret_cast<const bf16x8*>(qbase + 32);
    const int* mrow = mask + b * 1024;

    // scores = Q K^T / 8, masked, into LDS
    for (int kt = 0; kt < 1024; kt += 16) {
        const bf16* kbase = Kb + ((size_t)(b * 1024 + kt + r)) * DM + h * 64 + q * 8;
        bf16x8 kf0 = *reinterpret_cast<const bf16x8*>(kbase);
        bf16x8 kf1 = *reinterpret_cast<const bf16x8*>(kbase + 32);
        f32x4 acc = {};
        acc = __builtin_amdgcn_mfma_f32_16x16x32_bf16(qf0, kf0, acc, 0, 0, 0);
        acc = __builtin_amdgcn_mfma_f32_16x16x32_bf16(qf1, kf1, acc, 0, 0, 0);
        int col = kt + r;
        float mv = (mrow[col] == 0) ? -1e9f : 0.0f;
        #pragma unroll
        for (int i = 0; i < 4; ++i) {
            float v = acc[i] * 0.125f;
            if (mv != 0.0f) v = -1e9f;
            sc[q * 4 + i][col] = v;
        }
    }
    __syncthreads();

    // softmax: 4 lanes per row; keep unnormalized exp, defer 1/denom
    float rowsum = 0.f;
    {
        int row = lane >> 2, sub = lane & 3;
        float mx = -1e30f;
        for (int kk = sub; kk < 1024; kk += 4) mx = fmaxf(mx, sc[row][kk]);
        mx = fmaxf(mx, __shfl_xor(mx, 1));
        mx = fmaxf(mx, __shfl_xor(mx, 2));
        float sum = 0.f;
        for (int kk = sub; kk < 1024; kk += 4) {
            float e = expf(sc[row][kk] - mx);
            sc[row][kk] = e;
            sum += e;
        }
        sum += __shfl_xor(sum, 1);
        sum += __shfl_xor(sum, 2);
        rowsum = sum;                 // all 4 lanes of the row hold the full sum
    }
    __syncthreads();

    // PV: out[16 x 64] = P(16x1024) @ V(1024x64); Vt gives contiguous k loads
    #pragma unroll
    for (int nt = 0; nt < 4; ++nt) {
        f32x4 acc = {};
        for (int k0 = 0; k0 < 1024; k0 += 32) {
            bf16x8 pf;
            const float* prow = &sc[r][k0 + q * 8];
            #pragma unroll
            for (int j = 0; j < 8; ++j) pf[j] = (bf16)prow[j];
            const bf16* vbase = Vt + ((size_t)((b * 16 + h) * 64 + nt * 16 + r)) * 1024 + k0 + q * 8;
            bf16x8 vf = *reinterpret_cast<const bf16x8*>(vbase);
            acc = __builtin_amdgcn_mfma_f32_16x16x32_bf16(pf, vf, acc, 0, 0, 0);
        }
        #pragma unroll
        for (int i = 0; i < 4; ++i) {
            int mm = q * 4 + i;
            float d = __shfl(rowsum, mm * 4);   // lane mm*4 owns row mm's sum
            float v = acc[i] / d;
            out[((size_t)(b * 1024 + qt * 16 + mm)) * DM + h * 64 + nt * 16 + r] = (bf16)v;
        }
    }
}

// ---------------------------------------------------------------------------
extern "C" void kernel_launch(void* const* d_in, const int* in_sizes, int n_in,
                              void* d_out, int out_size, void* d_ws, size_t ws_size,
                              hipStream_t stream) {
    const float* x      = (const float*)d_in[0];
    const int*   mask   = (const int*)  d_in[1];
    const float* w_q    = (const float*)d_in[2];
    const float* w_k    = (const float*)d_in[3];
    const float* w_v    = (const float*)d_in[4];
    const float* w_o    = (const float*)d_in[5];
    const float* alpha1 = (const float*)d_in[6];
    const float* beta1  = (const float*)d_in[7];
    const float* alpha2 = (const float*)d_in[8];
    const float* beta2  = (const float*)d_in[9];
    const float* fc1_w  = (const float*)d_in[10];
    const float* fc1_b  = (const float*)d_in[11];
    const float* fc2_w  = (const float*)d_in[12];
    const float* fc2_b  = (const float*)d_in[13];
    float* out = (float*)d_out;

    char* ws = (char*)d_ws;
    const size_t MB = 1024 * 1024;
    bf16*  wq_b  = (bf16*)(ws +  0 * MB);
    bf16*  wk_b  = (bf16*)(ws +  2 * MB);
    bf16*  wv_b  = (bf16*)(ws +  4 * MB);
    bf16*  wo_b  = (bf16*)(ws +  6 * MB);
    bf16*  f1w_b = (bf16*)(ws +  8 * MB);
    bf16*  f2w_b = (bf16*)(ws + 16 * MB);
    bf16*  xn    = (bf16*)(ws + 24 * MB);   // ln1 out, reused for ln2 out
    bf16*  qb    = (bf16*)(ws + 28 * MB);
    bf16*  kb    = (bf16*)(ws + 32 * MB);
    bf16*  vb    = (bf16*)(ws + 36 * MB);
    bf16*  vtb   = (bf16*)(ws + 40 * MB);
    bf16*  attnb = (bf16*)(ws + 44 * MB);
    float* x2    = (float*)(ws + 48 * MB);
    bf16*  hb    = (bf16*)(ws + 28 * MB);   // reuse q/k/v/vt region (16 MB)

    // 1) weights -> bf16
    f2b4_kernel<<<1024, 256, 0, stream>>>((const float4*)w_q,   (bf16x4*)wq_b,  1024 * 1024 / 4);
    f2b4_kernel<<<1024, 256, 0, stream>>>((const float4*)w_k,   (bf16x4*)wk_b,  1024 * 1024 / 4);
    f2b4_kernel<<<1024, 256, 0, stream>>>((const float4*)w_v,   (bf16x4*)wv_b,  1024 * 1024 / 4);
    f2b4_kernel<<<1024, 256, 0, stream>>>((const float4*)w_o,   (bf16x4*)wo_b,  1024 * 1024 / 4);
    f2b4_kernel<<<4096, 256, 0, stream>>>((const float4*)fc1_w, (bf16x4*)f1w_b, 4096 * 1024 / 4);
    f2b4_kernel<<<4096, 256, 0, stream>>>((const float4*)fc2_w, (bf16x4*)f2w_b, 4096 * 1024 / 4);

    // 2) ln1
    ln_kernel<<<NTOK, 256, 0, stream>>>(x, alpha1, beta1, xn);

    // 3) q,k,v projections
    gemm_bt<0><<<dim3(16, 32), 256, 0, stream>>>(xn, wq_b, qb, nullptr, nullptr, NTOK, DM, DM);
    gemm_bt<0><<<dim3(16, 32), 256, 0, stream>>>(xn, wk_b, kb, nullptr, nullptr, NTOK, DM, DM);
    gemm_bt<0><<<dim3(16, 32), 256, 0, stream>>>(xn, wv_b, vb, nullptr, nullptr, NTOK, DM, DM);

    // 4) V -> (B,H,DK,S)
    transpose_v<<<dim3(32, 2, 32), dim3(32, 32), 0, stream>>>(vb, vtb);

    // 5) fused attention
    attn_kernel<<<2048, 64, 0, stream>>>(qb, kb, vtb, mask, attnb);

    // 6) o-proj + residual -> x2 (fp32)
    gemm_bt<3><<<dim3(16, 32), 256, 0, stream>>>(attnb, wo_b, x2, nullptr, x, NTOK, DM, DM);

    // 7) ln2
    ln_kernel<<<NTOK, 256, 0, stream>>>(x2, alpha2, beta2, xn);

    // 8) fc1 + bias + relu
    gemm_bt<1><<<dim3(64, 32), 256, 0, stream>>>(xn, f1w_b, hb, fc1_b, nullptr, NTOK, DFC, DM);

    // 9) fc2 + bias + residual -> out (fp32)
    gemm_bt<2><<<dim3(16, 32), 256, 0, stream>>>(hb, f2w_b, out, fc2_b, x2, NTOK, DM, DFC);
}

// Round 2
// 337.298 us; speedup vs baseline: 2.7078x; 2.7078x over previous
//
#include <hip/hip_runtime.h>
#include <hip/hip_bf16.h>

// ---------------------------------------------------------------------------
// EncoderBlock round 2:
//  - flash-style attention (online softmax, 1KB/wave LDS bounce for P C->A)
//  - m97-style LDS-staged GEMM: 64x128 block tile, BK=32, global_load_lds(16B)
//  - QKV fused into a single GEMM (N=3072)
// MFMA layouts (verified): A[m=lane&15][k=(lane>>4)*8+j],
//   B[k=(lane>>4)*8+j][n=lane&15], C/D row=(lane>>4)*4+reg, col=lane&15.
// ---------------------------------------------------------------------------

typedef __bf16 bf16;
typedef __attribute__((ext_vector_type(8))) __bf16 bf16x8;
typedef __attribute__((ext_vector_type(4))) __bf16 bf16x4;
typedef __attribute__((ext_vector_type(4))) float f32x4;

#define NTOK 2048
#define DM   1024
#define DFC  4096
#define QKVN 3072   // fused q|k|v output width

__device__ inline void gl_lds16(const void* g, void* l) {
    __builtin_amdgcn_global_load_lds((const __attribute__((address_space(1))) void*)g,
                                     (__attribute__((address_space(3))) void*)l, 16, 0, 0);
}

// ---------------- fp32 -> bf16 convert ----------------
__global__ __launch_bounds__(256) void f2b4_kernel(const float4* __restrict__ in,
                                                   bf16x4* __restrict__ out, int n4) {
    int i = blockIdx.x * 256 + threadIdx.x;
    if (i < n4) {
        float4 v = in[i];
        bf16x4 o;
        o[0] = (bf16)v.x; o[1] = (bf16)v.y; o[2] = (bf16)v.z; o[3] = (bf16)v.w;
        out[i] = o;
    }
}

// ---------------- LayerNorm (torch: std ddof=1, /(std+eps)) ----------------
__global__ __launch_bounds__(256) void ln_kernel(const float* __restrict__ x,
                                                 const float* __restrict__ alpha,
                                                 const float* __restrict__ beta,
                                                 bf16* __restrict__ out) {
    int row = blockIdx.x;
    int t = threadIdx.x;
    float4 v = reinterpret_cast<const float4*>(x + (size_t)row * DM)[t];
    float s  = v.x + v.y + v.z + v.w;
    float ss = v.x * v.x + v.y * v.y + v.z * v.z + v.w * v.w;
    __shared__ float red[8];
    int lane = t & 63, wv = t >> 6;
    #pragma unroll
    for (int o = 32; o > 0; o >>= 1) {
        s  += __shfl_down(s, o);
        ss += __shfl_down(ss, o);
    }
    if (lane == 0) { red[wv] = s; red[4 + wv] = ss; }
    __syncthreads();
    float S  = red[0] + red[1] + red[2] + red[3];
    float SS = red[4] + red[5] + red[6] + red[7];
    float mean = S * (1.0f / 1024.0f);
    float var  = (SS - S * mean) * (1.0f / 1023.0f);
    var = var < 0.f ? 0.f : var;
    float inv = 1.0f / (sqrtf(var) + 1e-6f);
    float4 a4 = reinterpret_cast<const float4*>(alpha)[t];
    float4 b4 = reinterpret_cast<const float4*>(beta)[t];
    bf16x4 o4;
    o4[0] = (bf16)(a4.x * (v.x - mean) * inv + b4.x);
    o4[1] = (bf16)(a4.y * (v.y - mean) * inv + b4.y);
    o4[2] = (bf16)(a4.z * (v.z - mean) * inv + b4.z);
    o4[3] = (bf16)(a4.w * (v.w - mean) * inv + b4.w);
    reinterpret_cast<bf16x4*>(out + (size_t)row * DM)[t] = o4;
}

// ---------------- GEMM: C = A @ Bt^T, LDS-staged (m97 pattern) --------------
// block tile 64(M) x 128(N), BK=32; 4 waves: wave w covers cols w*32..w*32+31
// global_load_lds: LDS dest = wave-uniform base + lane*16 (contiguous, no pad)
// EPI: 0 bf16; 1 relu(v+bias) bf16; 2 v+bias+resid f32; 3 v+resid f32
template <int EPI>
__global__ __launch_bounds__(256) void gemm_a64n128(const bf16* __restrict__ A,
                                                    const bf16* __restrict__ Bt,
                                                    void* __restrict__ outp,
                                                    const float* __restrict__ bias,
                                                    const float* __restrict__ resid,
                                                    int M, int N, int K) {
    __shared__ bf16 As[64 * 32];    // 4 KB, row-major [m][k], 64B rows
    __shared__ bf16 Bs[128 * 32];   // 8 KB, row-major [n][k]
    int lane = threadIdx.x & 63;
    int wave = threadIdx.x >> 6;
    int q = lane >> 4, r = lane & 15;
    int m0 = blockIdx.y * 64;
    int n0 = blockIdx.x * 128;
    f32x4 acc[4][2] = {};

    // staging addresses: lane i handles 16B chunk; row-in-chunk = i>>2, koff = (i&3)*8
    int srow = lane >> 2;
    int skof = (lane & 3) * 8;
    const bf16* agp = A  + (size_t)(m0 + wave * 16 + srow) * K + skof;
    const bf16* bgp0 = Bt + (size_t)(n0 + wave * 32 + srow) * K + skof;
    const bf16* bgp1 = bgp0 + (size_t)16 * K;
    bf16* alp  = As + wave * 512 + lane * 8;         // elems; *2 = bytes
    bf16* blp0 = Bs + wave * 1024 + lane * 8;
    bf16* blp1 = blp0 + 512;

    for (int k0 = 0; k0 < K; k0 += 32) {
        gl_lds16(agp + k0, alp);
        gl_lds16(bgp0 + k0, blp0);
        gl_lds16(bgp1 + k0, blp1);
        __syncthreads();
        bf16x8 af[4], bfr[2];
        #pragma unroll
        for (int t = 0; t < 4; ++t)
            af[t] = *reinterpret_cast<const bf16x8*>(As + (t * 16 + r) * 32 + q * 8);
        #pragma unroll
        for (int u = 0; u < 2; ++u)
            bfr[u] = *reinterpret_cast<const bf16x8*>(Bs + (wave * 32 + u * 16 + r) * 32 + q * 8);
        #pragma unroll
        for (int t = 0; t < 4; ++t)
            #pragma unroll
            for (int u = 0; u < 2; ++u)
                acc[t][u] = __builtin_amdgcn_mfma_f32_16x16x32_bf16(af[t], bfr[u], acc[t][u], 0, 0, 0);
        __syncthreads();
    }

    #pragma unroll
    for (int t = 0; t < 4; ++t) {
        #pragma unroll
        for (int u = 0; u < 2; ++u) {
            #pragma unroll
            for (int i = 0; i < 4; ++i) {
                int mm = m0 + t * 16 + q * 4 + i;
                int nn = n0 + wave * 32 + u * 16 + r;
                size_t idx = (size_t)mm * N + nn;
                float v = acc[t][u][i];
                if (EPI == 0) {
                    ((bf16*)outp)[idx] = (bf16)v;
                } else if (EPI == 1) {
                    v += bias[nn];
                    ((bf16*)outp)[idx] = (bf16)(v > 0.f ? v : 0.f);
                } else if (EPI == 2) {
                    ((float*)outp)[idx] = v + bias[nn] + resid[idx];
                } else {
                    ((float*)outp)[idx] = v + resid[idx];
                }
            }
        }
    }
}

// ---------------- V transpose: qkv[:, 2048+h*64+d] -> Vt (B,H,DK,S) ---------
__global__ void transpose_v(const bf16* __restrict__ qkv, bf16* __restrict__ vt) {
    __shared__ bf16 tile[32][33];
    int bh = blockIdx.z;
    int b = bh >> 4, h = bh & 15;
    int s0 = blockIdx.x * 32;
    int d0 = blockIdx.y * 32;
    int tx = threadIdx.x, ty = threadIdx.y;
    tile[ty][tx] = qkv[(size_t)(b * 1024 + s0 + ty) * QKVN + 2048 + h * 64 + d0 + tx];
    __syncthreads();
    vt[(size_t)(bh * 64 + d0 + ty) * 1024 + s0 + tx] = tile[tx][ty];
}

// ---------------- flash attention: 1 wave / 16 q-rows, online softmax -------
__global__ __launch_bounds__(256) void attn_kernel(const bf16* __restrict__ qkv,
                                                   const bf16* __restrict__ Vt,
                                                   const int* __restrict__ mask,
                                                   bf16* __restrict__ out) {
    __shared__ bf16 pbuf[4][16 * 32];   // 4 KB total, 1 KB per wave
    int lane = threadIdx.x & 63, wave = threadIdx.x >> 6;
    int q = lane >> 4, r = lane & 15;
    int id = blockIdx.x * 4 + wave;      // b*1024 + h*64 + qt
    int qt = id & 63, h = (id >> 6) & 15, b = id >> 10;

    const bf16* qbase = qkv + (size_t)(b * 1024 + qt * 16 + r) * QKVN + h * 64 + q * 8;
    bf16x8 qf0 = *reinterpret_cast<const bf16x8*>(qbase);
    bf16x8 qf1 = *reinterpret_cast<const bf16x8*>(qbase + 32);
    const bf16* kbase = qkv + (size_t)(b * 1024) * QKVN + 1024 + h * 64 + q * 8;
    const bf16* vbase = Vt + (size_t)((b * 16 + h) * 64) * 1024;
    const int* mrow = mask + b * 1024;
    bf16* pw = pbuf[wave];

    float m[4] = {-1e30f, -1e30f, -1e30f, -1e30f};
    float l[4] = {0.f, 0.f, 0.f, 0.f};
    f32x4 o[4] = {};

    for (int kt = 0; kt < 1024; kt += 32) {
        const bf16* kb0 = kbase + (size_t)(kt + r) * QKVN;
        const bf16* kb1 = kb0 + (size_t)16 * QKVN;
        f32x4 sA = {}, sB = {};
        sA = __builtin_amdgcn_mfma_f32_16x16x32_bf16(qf0, *reinterpret_cast<const bf16x8*>(kb0), sA, 0, 0, 0);
        sA = __builtin_amdgcn_mfma_f32_16x16x32_bf16(qf1, *reinterpret_cast<const bf16x8*>(kb0 + 32), sA, 0, 0, 0);
        sB = __builtin_amdgcn_mfma_f32_16x16x32_bf16(qf0, *reinterpret_cast<const bf16x8*>(kb1), sB, 0, 0, 0);
        sB = __builtin_amdgcn_mfma_f32_16x16x32_bf16(qf1, *reinterpret_cast<const bf16x8*>(kb1 + 32), sB, 0, 0, 0);
        bool okA = mrow[kt + r] != 0;
        bool okB = mrow[kt + 16 + r] != 0;
        #pragma unroll
        for (int i = 0; i < 4; ++i) {
            sA[i] = okA ? sA[i] * 0.125f : -1e9f;
            sB[i] = okB ? sB[i] * 0.125f : -1e9f;
        }
        float alpha[4], mn[4];
        #pragma unroll
        for (int i = 0; i < 4; ++i) {
            float t = fmaxf(sA[i], sB[i]);
            t = fmaxf(t, __shfl_xor(t, 1));
            t = fmaxf(t, __shfl_xor(t, 2));
            t = fmaxf(t, __shfl_xor(t, 4));
            t = fmaxf(t, __shfl_xor(t, 8));
            mn[i] = fmaxf(m[i], t);
            alpha[i] = __expf(m[i] - mn[i]);
            m[i] = mn[i];
        }
        #pragma unroll
        for (int i = 0; i < 4; ++i) {
            float pa = __expf(sA[i] - mn[i]);
            float pb = __expf(sB[i] - mn[i]);
            pw[(q * 4 + i) * 32 + r] = (bf16)pa;
            pw[(q * 4 + i) * 32 + 16 + r] = (bf16)pb;
            float rs = pa + pb;
            rs += __shfl_xor(rs, 1);
            rs += __shfl_xor(rs, 2);
            rs += __shfl_xor(rs, 4);
            rs += __shfl_xor(rs, 8);
            l[i] = l[i] * alpha[i] + rs;
            o[0][i] *= alpha[i]; o[1][i] *= alpha[i];
            o[2][i] *= alpha[i]; o[3][i] *= alpha[i];
        }
        // same-wave LDS write->read: compiler orders via lgkmcnt (no barrier needed)
        bf16x8 pf = *reinterpret_cast<const bf16x8*>(&pw[r * 32 + q * 8]);
        #pragma unroll
        for (int t = 0; t < 4; ++t) {
            bf16x8 vf = *reinterpret_cast<const bf16x8*>(vbase + (size_t)(t * 16 + r) * 1024 + kt + q * 8);
            o[t] = __builtin_amdgcn_mfma_f32_16x16x32_bf16(pf, vf, o[t], 0, 0, 0);
        }
    }

    float inv[4];
    #pragma unroll
    for (int i = 0; i < 4; ++i) inv[i] = 1.0f / l[i];
    #pragma unroll
    for (int t = 0; t < 4; ++t)
        #pragma unroll
        for (int i = 0; i < 4; ++i)
            out[(size_t)(b * 1024 + qt * 16 + q * 4 + i) * DM + h * 64 + t * 16 + r] =
                (bf16)(o[t][i] * inv[i]);
}

// ---------------------------------------------------------------------------
extern "C" void kernel_launch(void* const* d_in, const int* in_sizes, int n_in,
                              void* d_out, int out_size, void* d_ws, size_t ws_size,
                              hipStream_t stream) {
    const float* x      = (const float*)d_in[0];
    const int*   mask   = (const int*)  d_in[1];
    const float* w_q    = (const float*)d_in[2];
    const float* w_k    = (const float*)d_in[3];
    const float* w_v    = (const float*)d_in[4];
    const float* w_o    = (const float*)d_in[5];
    const float* alpha1 = (const float*)d_in[6];
    const float* beta1  = (const float*)d_in[7];
    const float* alpha2 = (const float*)d_in[8];
    const float* beta2  = (const float*)d_in[9];
    const float* fc1_w  = (const float*)d_in[10];
    const float* fc1_b  = (const float*)d_in[11];
    const float* fc2_w  = (const float*)d_in[12];
    const float* fc2_b  = (const float*)d_in[13];
    float* out = (float*)d_out;

    char* ws = (char*)d_ws;
    const size_t MB = 1024 * 1024;
    bf16*  wqkv_b = (bf16*)(ws +  0 * MB);   // 6 MB: wq|wk|wv rows concatenated
    bf16*  wo_b   = (bf16*)(ws +  6 * MB);   // 2 MB
    bf16*  f1w_b  = (bf16*)(ws +  8 * MB);   // 8 MB
    bf16*  f2w_b  = (bf16*)(ws + 16 * MB);   // 8 MB
    bf16*  xn     = (bf16*)(ws + 24 * MB);   // 4 MB (ln1 out, reused for ln2)
    bf16*  qkvb   = (bf16*)(ws + 28 * MB);   // 12 MB (2048 x 3072)
    bf16*  vtb    = (bf16*)(ws + 40 * MB);   // 4 MB
    bf16*  attnb  = (bf16*)(ws + 44 * MB);   // 4 MB
    float* x2     = (float*)(ws + 48 * MB);  // 8 MB
    bf16*  hb     = (bf16*)(ws + 28 * MB);   // 16 MB, reuses qkvb+vtb (dead by fc1)

    // 1) weights -> bf16 (q|k|v concatenated along rows)
    f2b4_kernel<<<1024, 256, 0, stream>>>((const float4*)w_q,   (bf16x4*)(wqkv_b),               1024 * 256);
    f2b4_kernel<<<1024, 256, 0, stream>>>((const float4*)w_k,   (bf16x4*)(wqkv_b + 1024 * 1024), 1024 * 256);
    f2b4_kernel<<<1024, 256, 0, stream>>>((const float4*)w_v,   (bf16x4*)(wqkv_b + 2048 * 1024), 1024 * 256);
    f2b4_kernel<<<1024, 256, 0, stream>>>((const float4*)w_o,   (bf16x4*)wo_b,  1024 * 256);
    f2b4_kernel<<<4096, 256, 0, stream>>>((const float4*)fc1_w, (bf16x4*)f1w_b, 4096 * 256);
    f2b4_kernel<<<4096, 256, 0, stream>>>((const float4*)fc2_w, (bf16x4*)f2w_b, 4096 * 256);

    // 2) ln1
    ln_kernel<<<NTOK, 256, 0, stream>>>(x, alpha1, beta1, xn);

    // 3) fused QKV projection: (2048x1024) @ (3072x1024)^T -> (2048x3072)
    gemm_a64n128<0><<<dim3(QKVN / 128, NTOK / 64), 256, 0, stream>>>(
        xn, wqkv_b, qkvb, nullptr, nullptr, NTOK, QKVN, DM);

    // 4) V -> (B,H,DK,S)
    transpose_v<<<dim3(32, 2, 32), dim3(32, 32), 0, stream>>>(qkvb, vtb);

    // 5) flash attention
    attn_kernel<<<512, 256, 0, stream>>>(qkvb, vtb, mask, attnb);

    // 6) o-proj + residual -> x2 (fp32)
    gemm_a64n128<3><<<dim3(DM / 128, NTOK / 64), 256, 0, stream>>>(
        attnb, wo_b, x2, nullptr, x, NTOK, DM, DM);

    // 7) ln2
    ln_kernel<<<NTOK, 256, 0, stream>>>(x2, alpha2, beta2, xn);

    // 8) fc1 + bias + relu
    gemm_a64n128<1><<<dim3(DFC / 128, NTOK / 64), 256, 0, stream>>>(
        xn, f1w_b, hb, fc1_b, nullptr, NTOK, DFC, DM);

    // 9) fc2 + bias + residual -> out (fp32)
    gemm_a64n128<2><<<dim3(DM / 128, NTOK / 64), 256, 0, stream>>>(
        hb, f2w_b, out, fc2_b, x2, NTOK, DM, DFC);
}

// Round 3
// 323.090 us; speedup vs baseline: 2.8269x; 1.0440x over previous
//
#include <hip/hip_runtime.h>
#include <hip/hip_bf16.h>

// ---------------------------------------------------------------------------
// EncoderBlock round 3:
//  - gemm128: m97-proven 128x128 tile, BK=32, 16 MFMA/wave/K-step, gl_lds(16B)
//  - split-K=2 for o-proj and fc2 (N=1024 -> grid 256), fp32 partials
//  - o-proj reduce fused with ln2 (block == row)
//  - all 6 weight fp32->bf16 conversions in one dispatch
// MFMA layouts (verified): A[m=lane&15][k=(lane>>4)*8+j],
//   B[k=(lane>>4)*8+j][n=lane&15], C/D row=(lane>>4)*4+reg, col=lane&15.
// ---------------------------------------------------------------------------

typedef __bf16 bf16;
typedef __attribute__((ext_vector_type(8))) __bf16 bf16x8;
typedef __attribute__((ext_vector_type(4))) __bf16 bf16x4;
typedef __attribute__((ext_vector_type(4))) float f32x4;

#define NTOK 2048
#define DM   1024
#define DFC  4096
#define QKVN 3072

__device__ inline void gl_lds16(const void* g, void* l) {
    __builtin_amdgcn_global_load_lds((const __attribute__((address_space(1))) void*)g,
                                     (__attribute__((address_space(3))) void*)l, 16, 0, 0);
}

// ---------------- all weights fp32 -> bf16, one dispatch --------------------
__global__ __launch_bounds__(256) void f2b_all_kernel(
    const float4* __restrict__ wq, const float4* __restrict__ wk,
    const float4* __restrict__ wv, const float4* __restrict__ wo,
    const float4* __restrict__ f1, const float4* __restrict__ f2,
    bf16x4* __restrict__ oqkv, bf16x4* __restrict__ oo,
    bf16x4* __restrict__ of1, bf16x4* __restrict__ of2) {
    int i = blockIdx.x * 256 + threadIdx.x;      // 0 .. 12*Q-1
    const int Q = 262144;                        // 1024*1024/4
    float4 v;
    bf16x4* dst;
    if (i < 3 * Q) {
        v = (i < Q) ? wq[i] : (i < 2 * Q) ? wk[i - Q] : wv[i - 2 * Q];
        dst = oqkv + i;
    } else if (i < 4 * Q) {
        v = wo[i - 3 * Q];
        dst = oo + (i - 3 * Q);
    } else if (i < 8 * Q) {
        v = f1[i - 4 * Q];
        dst = of1 + (i - 4 * Q);
    } else {
        v = f2[i - 8 * Q];
        dst = of2 + (i - 8 * Q);
    }
    bf16x4 o;
    o[0] = (bf16)v.x; o[1] = (bf16)v.y; o[2] = (bf16)v.z; o[3] = (bf16)v.w;
    *dst = o;
}

// ---------------- LayerNorm (torch: std ddof=1, /(std+eps)) ----------------
__device__ inline void ln_row(float4 v, const float* alpha, const float* beta,
                              bf16* outrow, int t) {
    float s  = v.x + v.y + v.z + v.w;
    float ss = v.x * v.x + v.y * v.y + v.z * v.z + v.w * v.w;
    __shared__ float red[8];
    int lane = t & 63, wv = t >> 6;
    #pragma unroll
    for (int o = 32; o > 0; o >>= 1) {
        s  += __shfl_down(s, o);
        ss += __shfl_down(ss, o);
    }
    if (lane == 0) { red[wv] = s; red[4 + wv] = ss; }
    __syncthreads();
    float S  = red[0] + red[1] + red[2] + red[3];
    float SS = red[4] + red[5] + red[6] + red[7];
    float mean = S * (1.0f / 1024.0f);
    float var  = (SS - S * mean) * (1.0f / 1023.0f);
    var = var < 0.f ? 0.f : var;
    float inv = 1.0f / (sqrtf(var) + 1e-6f);
    float4 a4 = reinterpret_cast<const float4*>(alpha)[t];
    float4 b4 = reinterpret_cast<const float4*>(beta)[t];
    bf16x4 o4;
    o4[0] = (bf16)(a4.x * (v.x - mean) * inv + b4.x);
    o4[1] = (bf16)(a4.y * (v.y - mean) * inv + b4.y);
    o4[2] = (bf16)(a4.z * (v.z - mean) * inv + b4.z);
    o4[3] = (bf16)(a4.w * (v.w - mean) * inv + b4.w);
    reinterpret_cast<bf16x4*>(outrow)[t] = o4;
}

__global__ __launch_bounds__(256) void ln_kernel(const float* __restrict__ x,
                                                 const float* __restrict__ alpha,
                                                 const float* __restrict__ beta,
                                                 bf16* __restrict__ out) {
    int row = blockIdx.x, t = threadIdx.x;
    float4 v = reinterpret_cast<const float4*>(x + (size_t)row * DM)[t];
    ln_row(v, alpha, beta, out + (size_t)row * DM, t);
}

// ---- o-proj split-K reduce + residual -> x2, fused ln2 -> xn (block=row) ---
__global__ __launch_bounds__(256) void reduce_ln_kernel(const float* __restrict__ p,
                                                        const float* __restrict__ resid,
                                                        const float* __restrict__ alpha,
                                                        const float* __restrict__ beta,
                                                        float* __restrict__ x2,
                                                        bf16* __restrict__ xn) {
    int row = blockIdx.x, t = threadIdx.x;
    size_t i4 = (size_t)row * 256 + t;
    float4 a = reinterpret_cast<const float4*>(p)[i4];
    float4 b = reinterpret_cast<const float4*>(p)[i4 + 524288];  // slice 1
    float4 r = reinterpret_cast<const float4*>(resid)[i4];
    float4 v;
    v.x = a.x + b.x + r.x; v.y = a.y + b.y + r.y;
    v.z = a.z + b.z + r.z; v.w = a.w + b.w + r.w;
    reinterpret_cast<float4*>(x2)[i4] = v;
    ln_row(v, alpha, beta, xn + (size_t)row * DM, t);
}

// ---- fc2 split-K reduce + bias + residual -> d_out (fp32) ------------------
__global__ __launch_bounds__(256) void reduce_out_kernel(const float* __restrict__ p,
                                                         const float* __restrict__ bias,
                                                         const float* __restrict__ x2,
                                                         float* __restrict__ out) {
    size_t i4 = (size_t)blockIdx.x * 256 + threadIdx.x;
    float4 a = reinterpret_cast<const float4*>(p)[i4];
    float4 b = reinterpret_cast<const float4*>(p)[i4 + 524288];
    float4 r = reinterpret_cast<const float4*>(x2)[i4];
    float4 bi = reinterpret_cast<const float4*>(bias)[i4 & 255];   // N/4 = 256
    float4 o;
    o.x = a.x + b.x + r.x + bi.x; o.y = a.y + b.y + r.y + bi.y;
    o.z = a.z + b.z + r.z + bi.z; o.w = a.w + b.w + r.w + bi.w;
    reinterpret_cast<float4*>(out)[i4] = o;
}

// ---------------- GEMM: 128x128 tile, C = A @ Bt^T --------------------------
// 4 waves in 2x2; wave tile 64x64 (4x4 16x16 acc); BK=32.
// EPI: 0 = store bf16; 1 = relu(v+bias) bf16; 4 = fp32 partial at z*M*N
template <int EPI>
__global__ __launch_bounds__(256) void gemm128(const bf16* __restrict__ A,
                                               const bf16* __restrict__ Bt,
                                               void* __restrict__ outp,
                                               const float* __restrict__ bias,
                                               int M, int N, int K, int kslice) {
    __shared__ bf16 As[128 * 32];   // 8 KB row-major [m][k]
    __shared__ bf16 Bs[128 * 32];   // 8 KB row-major [n][k]
    int lane = threadIdx.x & 63, wave = threadIdx.x >> 6;
    int q = lane >> 4, r = lane & 15;
    int wm = wave >> 1, wn = wave & 1;
    int m0 = blockIdx.y * 128, n0 = blockIdx.x * 128;
    int kbeg = blockIdx.z * kslice, kend = kbeg + kslice;
    f32x4 acc[4][4] = {};

    int srow = lane >> 2, skof = (lane & 3) * 8;
    const bf16* ag0 = A  + (size_t)(m0 + wave * 16 + srow) * K + skof;
    const bf16* ag1 = ag0 + (size_t)64 * K;
    const bf16* bg0 = Bt + (size_t)(n0 + wave * 16 + srow) * K + skof;
    const bf16* bg1 = bg0 + (size_t)64 * K;
    bf16* al0 = As + wave * 512 + lane * 8;
    bf16* al1 = al0 + 2048;
    bf16* bl0 = Bs + wave * 512 + lane * 8;
    bf16* bl1 = bl0 + 2048;

    for (int k0 = kbeg; k0 < kend; k0 += 32) {
        gl_lds16(ag0 + k0, al0);
        gl_lds16(ag1 + k0, al1);
        gl_lds16(bg0 + k0, bl0);
        gl_lds16(bg1 + k0, bl1);
        __syncthreads();
        bf16x8 af[4], bfv[4];
        #pragma unroll
        for (int t = 0; t < 4; ++t)
            af[t] = *reinterpret_cast<const bf16x8*>(As + (wm * 64 + t * 16 + r) * 32 + q * 8);
        #pragma unroll
        for (int u = 0; u < 4; ++u)
            bfv[u] = *reinterpret_cast<const bf16x8*>(Bs + (wn * 64 + u * 16 + r) * 32 + q * 8);
        #pragma unroll
        for (int t = 0; t < 4; ++t)
            #pragma unroll
            for (int u = 0; u < 4; ++u)
                acc[t][u] = __builtin_amdgcn_mfma_f32_16x16x32_bf16(af[t], bfv[u], acc[t][u], 0, 0, 0);
        __syncthreads();
    }

    size_t zoff = (size_t)blockIdx.z * M * N;
    #pragma unroll
    for (int t = 0; t < 4; ++t) {
        #pragma unroll
        for (int u = 0; u < 4; ++u) {
            #pragma unroll
            for (int i = 0; i < 4; ++i) {
                int mm = m0 + wm * 64 + t * 16 + q * 4 + i;
                int nn = n0 + wn * 64 + u * 16 + r;
                size_t idx = (size_t)mm * N + nn;
                float v = acc[t][u][i];
                if (EPI == 0) {
                    ((bf16*)outp)[idx] = (bf16)v;
                } else if (EPI == 1) {
                    v += bias[nn];
                    ((bf16*)outp)[idx] = (bf16)(v > 0.f ? v : 0.f);
                } else {
                    ((float*)outp)[zoff + idx] = v;
                }
            }
        }
    }
}

// ---------------- V transpose: qkv[:, 2048+h*64+d] -> Vt (B,H,DK,S) ---------
__global__ void transpose_v(const bf16* __restrict__ qkv, bf16* __restrict__ vt) {
    __shared__ bf16 tile[32][33];
    int bh = blockIdx.z;
    int b = bh >> 4, h = bh & 15;
    int s0 = blockIdx.x * 32;
    int d0 = blockIdx.y * 32;
    int tx = threadIdx.x, ty = threadIdx.y;
    tile[ty][tx] = qkv[(size_t)(b * 1024 + s0 + ty) * QKVN + 2048 + h * 64 + d0 + tx];
    __syncthreads();
    vt[(size_t)(bh * 64 + d0 + ty) * 1024 + s0 + tx] = tile[tx][ty];
}

// ---------------- flash attention: 1 wave / 16 q-rows, online softmax -------
__global__ __launch_bounds__(256) void attn_kernel(const bf16* __restrict__ qkv,
                                                   const bf16* __restrict__ Vt,
                                                   const int* __restrict__ mask,
                                                   bf16* __restrict__ out) {
    __shared__ bf16 pbuf[4][16 * 32];
    int lane = threadIdx.x & 63, wave = threadIdx.x >> 6;
    int q = lane >> 4, r = lane & 15;
    int id = blockIdx.x * 4 + wave;
    int qt = id & 63, h = (id >> 6) & 15, b = id >> 10;

    const bf16* qbase = qkv + (size_t)(b * 1024 + qt * 16 + r) * QKVN + h * 64 + q * 8;
    bf16x8 qf0 = *reinterpret_cast<const bf16x8*>(qbase);
    bf16x8 qf1 = *reinterpret_cast<const bf16x8*>(qbase + 32);
    const bf16* kbase = qkv + (size_t)(b * 1024) * QKVN + 1024 + h * 64 + q * 8;
    const bf16* vbase = Vt + (size_t)((b * 16 + h) * 64) * 1024;
    const int* mrow = mask + b * 1024;
    bf16* pw = pbuf[wave];

    float m[4] = {-1e30f, -1e30f, -1e30f, -1e30f};
    float l[4] = {0.f, 0.f, 0.f, 0.f};
    f32x4 o[4] = {};

    for (int kt = 0; kt < 1024; kt += 32) {
        const bf16* kb0 = kbase + (size_t)(kt + r) * QKVN;
        const bf16* kb1 = kb0 + (size_t)16 * QKVN;
        f32x4 sA = {}, sB = {};
        sA = __builtin_amdgcn_mfma_f32_16x16x32_bf16(qf0, *reinterpret_cast<const bf16x8*>(kb0), sA, 0, 0, 0);
        sA = __builtin_amdgcn_mfma_f32_16x16x32_bf16(qf1, *reinterpret_cast<const bf16x8*>(kb0 + 32), sA, 0, 0, 0);
        sB = __builtin_amdgcn_mfma_f32_16x16x32_bf16(qf0, *reinterpret_cast<const bf16x8*>(kb1), sB, 0, 0, 0);
        sB = __builtin_amdgcn_mfma_f32_16x16x32_bf16(qf1, *reinterpret_cast<const bf16x8*>(kb1 + 32), sB, 0, 0, 0);
        bool okA = mrow[kt + r] != 0;
        bool okB = mrow[kt + 16 + r] != 0;
        #pragma unroll
        for (int i = 0; i < 4; ++i) {
            sA[i] = okA ? sA[i] * 0.125f : -1e9f;
            sB[i] = okB ? sB[i] * 0.125f : -1e9f;
        }
        float alpha[4], mn[4];
        #pragma unroll
        for (int i = 0; i < 4; ++i) {
            float t = fmaxf(sA[i], sB[i]);
            t = fmaxf(t, __shfl_xor(t, 1));
            t = fmaxf(t, __shfl_xor(t, 2));
            t = fmaxf(t, __shfl_xor(t, 4));
            t = fmaxf(t, __shfl_xor(t, 8));
            mn[i] = fmaxf(m[i], t);
            alpha[i] = __expf(m[i] - mn[i]);
            m[i] = mn[i];
        }
        #pragma unroll
        for (int i = 0; i < 4; ++i) {
            float pa = __expf(sA[i] - mn[i]);
            float pb = __expf(sB[i] - mn[i]);
            pw[(q * 4 + i) * 32 + r] = (bf16)pa;
            pw[(q * 4 + i) * 32 + 16 + r] = (bf16)pb;
            float rs = pa + pb;
            rs += __shfl_xor(rs, 1);
            rs += __shfl_xor(rs, 2);
            rs += __shfl_xor(rs, 4);
            rs += __shfl_xor(rs, 8);
            l[i] = l[i] * alpha[i] + rs;
            o[0][i] *= alpha[i]; o[1][i] *= alpha[i];
            o[2][i] *= alpha[i]; o[3][i] *= alpha[i];
        }
        bf16x8 pf = *reinterpret_cast<const bf16x8*>(&pw[r * 32 + q * 8]);
        #pragma unroll
        for (int t = 0; t < 4; ++t) {
            bf16x8 vf = *reinterpret_cast<const bf16x8*>(vbase + (size_t)(t * 16 + r) * 1024 + kt + q * 8);
            o[t] = __builtin_amdgcn_mfma_f32_16x16x32_bf16(pf, vf, o[t], 0, 0, 0);
        }
    }

    float inv[4];
    #pragma unroll
    for (int i = 0; i < 4; ++i) inv[i] = 1.0f / l[i];
    #pragma unroll
    for (int t = 0; t < 4; ++t)
        #pragma unroll
        for (int i = 0; i < 4; ++i)
            out[(size_t)(b * 1024 + qt * 16 + q * 4 + i) * DM + h * 64 + t * 16 + r] =
                (bf16)(o[t][i] * inv[i]);
}

// ---------------------------------------------------------------------------
extern "C" void kernel_launch(void* const* d_in, const int* in_sizes, int n_in,
                              void* d_out, int out_size, void* d_ws, size_t ws_size,
                              hipStream_t stream) {
    const float* x      = (const float*)d_in[0];
    const int*   mask   = (const int*)  d_in[1];
    const float* w_q    = (const float*)d_in[2];
    const float* w_k    = (const float*)d_in[3];
    const float* w_v    = (const float*)d_in[4];
    const float* w_o    = (const float*)d_in[5];
    const float* alpha1 = (const float*)d_in[6];
    const float* beta1  = (const float*)d_in[7];
    const float* alpha2 = (const float*)d_in[8];
    const float* beta2  = (const float*)d_in[9];
    const float* fc1_w  = (const float*)d_in[10];
    const float* fc1_b  = (const float*)d_in[11];
    const float* fc2_w  = (const float*)d_in[12];
    const float* fc2_b  = (const float*)d_in[13];
    float* out = (float*)d_out;

    char* ws = (char*)d_ws;
    const size_t MB = 1024 * 1024;
    // Timeline-aware layout (max 56 MB):
    bf16*  wqkv_b = (bf16*)(ws +  0 * MB);   // 6 MB   (dead after QKV gemm)
    bf16*  wo_b   = (bf16*)(ws +  6 * MB);   // 2 MB   (dead after o-proj)
    bf16*  f1w_b  = (bf16*)(ws +  8 * MB);   // 8 MB   (dead after fc1)
    bf16*  f2w_b  = (bf16*)(ws + 16 * MB);   // 8 MB
    bf16*  xn     = (bf16*)(ws + 24 * MB);   // 4 MB
    bf16*  qkvb   = (bf16*)(ws + 28 * MB);   // 12 MB  (dead after attn)
    bf16*  vtb    = (bf16*)(ws + 40 * MB);   // 4 MB   (dead after attn)
    bf16*  attnb  = (bf16*)(ws + 44 * MB);   // 4 MB   (dead after o-proj)
    float* x2     = (float*)(ws + 48 * MB);  // 8 MB
    float* po     = (float*)(ws + 28 * MB);  // 16 MB o-proj partials (over qkvb+vtb)
    bf16*  hb     = (bf16*)(ws + 28 * MB);   // 16 MB fc1 out (over po, dead)
    float* pf2    = (float*)(ws +  0 * MB);  // 16 MB fc2 partials (over wqkv/wo/f1w)

    // 1) all weights -> bf16, one dispatch
    f2b_all_kernel<<<12288, 256, 0, stream>>>(
        (const float4*)w_q, (const float4*)w_k, (const float4*)w_v, (const float4*)w_o,
        (const float4*)fc1_w, (const float4*)fc2_w,
        (bf16x4*)wqkv_b, (bf16x4*)wo_b, (bf16x4*)f1w_b, (bf16x4*)f2w_b);

    // 2) ln1
    ln_kernel<<<NTOK, 256, 0, stream>>>(x, alpha1, beta1, xn);

    // 3) fused QKV projection: (2048x1024)@(3072x1024)^T
    gemm128<0><<<dim3(QKVN / 128, NTOK / 128, 1), 256, 0, stream>>>(
        xn, wqkv_b, qkvb, nullptr, NTOK, QKVN, DM, DM);

    // 4) V -> (B,H,DK,S)
    transpose_v<<<dim3(32, 2, 32), dim3(32, 32), 0, stream>>>(qkvb, vtb);

    // 5) flash attention
    attn_kernel<<<512, 256, 0, stream>>>(qkvb, vtb, mask, attnb);

    // 6) o-proj split-K=2 partials (attnb input; partials over dead qkv region)
    gemm128<4><<<dim3(DM / 128, NTOK / 128, 2), 256, 0, stream>>>(
        attnb, wo_b, po, nullptr, NTOK, DM, DM, DM / 2);

    // 7) reduce + residual -> x2, fused ln2 -> xn
    reduce_ln_kernel<<<NTOK, 256, 0, stream>>>(po, x, alpha2, beta2, x2, xn);

    // 8) fc1 + bias + relu -> hb
    gemm128<1><<<dim3(DFC / 128, NTOK / 128, 1), 256, 0, stream>>>(
        xn, f1w_b, hb, fc1_b, NTOK, DFC, DM, DM);

    // 9) fc2 split-K=2 partials (weights regions dead by now)
    gemm128<4><<<dim3(DM / 128, NTOK / 128, 2), 256, 0, stream>>>(
        hb, f2w_b, pf2, nullptr, NTOK, DM, DFC, DFC / 2);

    // 10) reduce + bias + residual -> out (fp32)
    reduce_out_kernel<<<2048, 256, 0, stream>>>(pf2, fc2_b, x2, out);
}

// Round 5
// 300.765 us; speedup vs baseline: 3.0367x; 1.0742x over previous
//
#include <hip/hip_runtime.h>
#include <hip/hip_bf16.h>

// ---------------------------------------------------------------------------
// EncoderBlock round 5:
//  - attention: EXACT softmax (true row max), scores held in registers per
//    256-key slice; 4 slices/block; exact exp(m_s - m_tot) combine in LDS.
//    (round 4's fixed-shift no-max softmax caused absmax 0.28 -> reverted)
//  - gemm128: BK=64, XOR-swizzled LDS (hand-verified 3x), 32 MFMA/barrier
// MFMA layouts (verified): A[m=lane&15][k=(lane>>4)*8+j],
//   B[k=(lane>>4)*8+j][n=lane&15], C/D row=(lane>>4)*4+reg, col=lane&15.
// ---------------------------------------------------------------------------

typedef __bf16 bf16;
typedef __attribute__((ext_vector_type(8))) __bf16 bf16x8;
typedef __attribute__((ext_vector_type(4))) __bf16 bf16x4;
typedef __attribute__((ext_vector_type(4))) float f32x4;

#define NTOK 2048
#define DM   1024
#define DFC  4096
#define QKVN 3072

__device__ inline void gl_lds16(const void* g, void* l) {
    __builtin_amdgcn_global_load_lds((const __attribute__((address_space(1))) void*)g,
                                     (__attribute__((address_space(3))) void*)l, 16, 0, 0);
}

// ---------------- all weights fp32 -> bf16, one dispatch --------------------
__global__ __launch_bounds__(256) void f2b_all_kernel(
    const float4* __restrict__ wq, const float4* __restrict__ wk,
    const float4* __restrict__ wv, const float4* __restrict__ wo,
    const float4* __restrict__ f1, const float4* __restrict__ f2,
    bf16x4* __restrict__ oqkv, bf16x4* __restrict__ oo,
    bf16x4* __restrict__ of1, bf16x4* __restrict__ of2) {
    int i = blockIdx.x * 256 + threadIdx.x;
    const int Q = 262144;                        // 1024*1024/4
    float4 v;
    bf16x4* dst;
    if (i < 3 * Q) {
        v = (i < Q) ? wq[i] : (i < 2 * Q) ? wk[i - Q] : wv[i - 2 * Q];
        dst = oqkv + i;
    } else if (i < 4 * Q) {
        v = wo[i - 3 * Q];
        dst = oo + (i - 3 * Q);
    } else if (i < 8 * Q) {
        v = f1[i - 4 * Q];
        dst = of1 + (i - 4 * Q);
    } else {
        v = f2[i - 8 * Q];
        dst = of2 + (i - 8 * Q);
    }
    bf16x4 o;
    o[0] = (bf16)v.x; o[1] = (bf16)v.y; o[2] = (bf16)v.z; o[3] = (bf16)v.w;
    *dst = o;
}

// ---------------- LayerNorm (torch: std ddof=1, /(std+eps)) ----------------
__device__ inline void ln_row(float4 v, const float* alpha, const float* beta,
                              bf16* outrow, int t) {
    float s  = v.x + v.y + v.z + v.w;
    float ss = v.x * v.x + v.y * v.y + v.z * v.z + v.w * v.w;
    __shared__ float red[8];
    int lane = t & 63, wv = t >> 6;
    #pragma unroll
    for (int o = 32; o > 0; o >>= 1) {
        s  += __shfl_down(s, o);
        ss += __shfl_down(ss, o);
    }
    if (lane == 0) { red[wv] = s; red[4 + wv] = ss; }
    __syncthreads();
    float S  = red[0] + red[1] + red[2] + red[3];
    float SS = red[4] + red[5] + red[6] + red[7];
    float mean = S * (1.0f / 1024.0f);
    float var  = (SS - S * mean) * (1.0f / 1023.0f);
    var = var < 0.f ? 0.f : var;
    float inv = 1.0f / (sqrtf(var) + 1e-6f);
    float4 a4 = reinterpret_cast<const float4*>(alpha)[t];
    float4 b4 = reinterpret_cast<const float4*>(beta)[t];
    bf16x4 o4;
    o4[0] = (bf16)(a4.x * (v.x - mean) * inv + b4.x);
    o4[1] = (bf16)(a4.y * (v.y - mean) * inv + b4.y);
    o4[2] = (bf16)(a4.z * (v.z - mean) * inv + b4.z);
    o4[3] = (bf16)(a4.w * (v.w - mean) * inv + b4.w);
    reinterpret_cast<bf16x4*>(outrow)[t] = o4;
}

__global__ __launch_bounds__(256) void ln_kernel(const float* __restrict__ x,
                                                 const float* __restrict__ alpha,
                                                 const float* __restrict__ beta,
                                                 bf16* __restrict__ out) {
    int row = blockIdx.x, t = threadIdx.x;
    float4 v = reinterpret_cast<const float4*>(x + (size_t)row * DM)[t];
    ln_row(v, alpha, beta, out + (size_t)row * DM, t);
}

// ---- o-proj split-K reduce + residual -> x2, fused ln2 -> xn (block=row) ---
__global__ __launch_bounds__(256) void reduce_ln_kernel(const float* __restrict__ p,
                                                        const float* __restrict__ resid,
                                                        const float* __restrict__ alpha,
                                                        const float* __restrict__ beta,
                                                        float* __restrict__ x2,
                                                        bf16* __restrict__ xn) {
    int row = blockIdx.x, t = threadIdx.x;
    size_t i4 = (size_t)row * 256 + t;
    float4 a = reinterpret_cast<const float4*>(p)[i4];
    float4 b = reinterpret_cast<const float4*>(p)[i4 + 524288];
    float4 r = reinterpret_cast<const float4*>(resid)[i4];
    float4 v;
    v.x = a.x + b.x + r.x; v.y = a.y + b.y + r.y;
    v.z = a.z + b.z + r.z; v.w = a.w + b.w + r.w;
    reinterpret_cast<float4*>(x2)[i4] = v;
    ln_row(v, alpha, beta, xn + (size_t)row * DM, t);
}

// ---- fc2 split-K reduce + bias + residual -> d_out (fp32) ------------------
__global__ __launch_bounds__(256) void reduce_out_kernel(const float* __restrict__ p,
                                                         const float* __restrict__ bias,
                                                         const float* __restrict__ x2,
                                                         float* __restrict__ out) {
    size_t i4 = (size_t)blockIdx.x * 256 + threadIdx.x;
    float4 a = reinterpret_cast<const float4*>(p)[i4];
    float4 b = reinterpret_cast<const float4*>(p)[i4 + 524288];
    float4 r = reinterpret_cast<const float4*>(x2)[i4];
    float4 bi = reinterpret_cast<const float4*>(bias)[i4 & 255];
    float4 o;
    o.x = a.x + b.x + r.x + bi.x; o.y = a.y + b.y + r.y + bi.y;
    o.z = a.z + b.z + r.z + bi.z; o.w = a.w + b.w + r.w + bi.w;
    reinterpret_cast<float4*>(out)[i4] = o;
}

// ---------------- GEMM: 128x128 tile, BK=64, swizzled LDS -------------------
// LDS layout: 8-elem chunk c of row m stored at pos = c ^ (m&7); row stride
// 128B -> ds_read_b128 is 2-way-bank (free). gl_lds dest stays lane*16B.
// EPI: 0 = store bf16; 1 = relu(v+bias) bf16; 4 = fp32 partial at z*M*N
template <int EPI>
__global__ __launch_bounds__(256) void gemm128(const bf16* __restrict__ A,
                                               const bf16* __restrict__ Bt,
                                               void* __restrict__ outp,
                                               const float* __restrict__ bias,
                                               int M, int N, int K, int kslice) {
    __shared__ bf16 As[128 * 64];   // 16 KB
    __shared__ bf16 Bs[128 * 64];   // 16 KB
    int tid = threadIdx.x;
    int lane = tid & 63, wave = tid >> 6;
    int q = lane >> 4, r = lane & 15;
    int wm = wave >> 1, wn = wave & 1;
    int m0 = blockIdx.y * 128, n0 = blockIdx.x * 128;
    int kbeg = blockIdx.z * kslice, kend = kbeg + kslice;
    f32x4 acc[4][4] = {};

    int srow = tid >> 3;                       // 0..31 (j adds 32 each)
    int csrc = (tid & 7) ^ (srow & 7);         // source chunk for this pos
    const bf16* agp = A  + (size_t)(m0 + srow) * K + csrc * 8;
    const bf16* bgp = Bt + (size_t)(n0 + srow) * K + csrc * 8;
    bf16* alp = As + tid * 8;
    bf16* blp = Bs + tid * 8;

    int rsw = (r & 7);
    int co0 = ((q ^ rsw) * 8);
    int co1 = co0 ^ 32;
    const bf16* ara = As + (wm * 64 + r) * 64;
    const bf16* brb = Bs + (wn * 64 + r) * 64;

    for (int k0 = kbeg; k0 < kend; k0 += 64) {
        #pragma unroll
        for (int j = 0; j < 4; ++j) {
            gl_lds16(agp + (size_t)j * 32 * K + k0, alp + j * 2048);
            gl_lds16(bgp + (size_t)j * 32 * K + k0, blp + j * 2048);
        }
        __syncthreads();
        #pragma unroll
        for (int half = 0; half < 2; ++half) {
            int co = half ? co1 : co0;
            bf16x8 af[4], bfv[4];
            #pragma unroll
            for (int t = 0; t < 4; ++t)
                af[t] = *reinterpret_cast<const bf16x8*>(ara + t * 1024 + co);
            #pragma unroll
            for (int u = 0; u < 4; ++u)
                bfv[u] = *reinterpret_cast<const bf16x8*>(brb + u * 1024 + co);
            #pragma unroll
            for (int t = 0; t < 4; ++t)
                #pragma unroll
                for (int u = 0; u < 4; ++u)
                    acc[t][u] = __builtin_amdgcn_mfma_f32_16x16x32_bf16(af[t], bfv[u], acc[t][u], 0, 0, 0);
        }
        __syncthreads();
    }

    size_t zoff = (size_t)blockIdx.z * M * N;
    #pragma unroll
    for (int t = 0; t < 4; ++t) {
        #pragma unroll
        for (int u = 0; u < 4; ++u) {
            #pragma unroll
            for (int i = 0; i < 4; ++i) {
                int mm = m0 + wm * 64 + t * 16 + q * 4 + i;
                int nn = n0 + wn * 64 + u * 16 + r;
                size_t idx = (size_t)mm * N + nn;
                float v = acc[t][u][i];
                if (EPI == 0) {
                    ((bf16*)outp)[idx] = (bf16)v;
                } else if (EPI == 1) {
                    v += bias[nn];
                    ((bf16*)outp)[idx] = (bf16)(v > 0.f ? v : 0.f);
                } else {
                    ((float*)outp)[zoff + idx] = v;
                }
            }
        }
    }
}

// ---------------- V transpose: qkv[:, 2048+h*64+d] -> Vt (B,H,DK,S) ---------
__global__ void transpose_v(const bf16* __restrict__ qkv, bf16* __restrict__ vt) {
    __shared__ bf16 tile[32][33];
    int bh = blockIdx.z;
    int b = bh >> 4, h = bh & 15;
    int s0 = blockIdx.x * 32;
    int d0 = blockIdx.y * 32;
    int tx = threadIdx.x, ty = threadIdx.y;
    tile[ty][tx] = qkv[(size_t)(b * 1024 + s0 + ty) * QKVN + 2048 + h * 64 + d0 + tx];
    __syncthreads();
    vt[(size_t)(bh * 64 + d0 + ty) * 1024 + s0 + tx] = tile[tx][ty];
}

// ---------------- attention: EXACT softmax, registers, 4 key-slices ---------
// block = 1 q-tile (16 rows); wave s: keys [s*256, s*256+256).
// Pass 1: all 8 score tiles -> registers. True row max + exp + sum (once).
// Pass 2: PV via per-wave LDS bounce. Combine slices w/ exp(m_s - m_tot).
__global__ __launch_bounds__(256) void attn_kernel(const bf16* __restrict__ qkv,
                                                   const bf16* __restrict__ Vt,
                                                   const int* __restrict__ mask,
                                                   bf16* __restrict__ out) {
    __shared__ bf16  pbuf[4][16 * 32];   // 4 KB
    __shared__ float obuf[4][16][68];    // 17.4 KB
    __shared__ float lbuf[4][16];
    __shared__ float mbuf[4][16];
    int lane = threadIdx.x & 63, s = threadIdx.x >> 6;
    int q = lane >> 4, r = lane & 15;
    int id = blockIdx.x;                 // b*1024 + h*64 + qt
    int qt = id & 63, h = (id >> 6) & 15, b = id >> 10;

    const bf16* qbase = qkv + (size_t)(b * 1024 + qt * 16 + r) * QKVN + h * 64 + q * 8;
    bf16x8 qf0 = *reinterpret_cast<const bf16x8*>(qbase);
    bf16x8 qf1 = *reinterpret_cast<const bf16x8*>(qbase + 32);
    const bf16* kbase = qkv + (size_t)(b * 1024 + s * 256) * QKVN + 1024 + h * 64 + q * 8;
    const bf16* vbase = Vt + (size_t)((b * 16 + h) * 64) * 1024 + s * 256;
    const int* mrow = mask + b * 1024 + s * 256;
    bf16* pw = pbuf[s];

    // pass 1: all scores for this slice into registers
    f32x4 sc[8][2];
    #pragma unroll
    for (int t8 = 0; t8 < 8; ++t8) {
        int kt = t8 * 32;
        const bf16* kb0 = kbase + (size_t)(kt + r) * QKVN;
        const bf16* kb1 = kb0 + (size_t)16 * QKVN;
        f32x4 sA = {}, sB = {};
        sA = __builtin_amdgcn_mfma_f32_16x16x32_bf16(qf0, *reinterpret_cast<const bf16x8*>(kb0), sA, 0, 0, 0);
        sA = __builtin_amdgcn_mfma_f32_16x16x32_bf16(qf1, *reinterpret_cast<const bf16x8*>(kb0 + 32), sA, 0, 0, 0);
        sB = __builtin_amdgcn_mfma_f32_16x16x32_bf16(qf0, *reinterpret_cast<const bf16x8*>(kb1), sB, 0, 0, 0);
        sB = __builtin_amdgcn_mfma_f32_16x16x32_bf16(qf1, *reinterpret_cast<const bf16x8*>(kb1 + 32), sB, 0, 0, 0);
        bool okA = mrow[kt + r] != 0;
        bool okB = mrow[kt + 16 + r] != 0;
        #pragma unroll
        for (int i = 0; i < 4; ++i) {
            sc[t8][0][i] = okA ? sA[i] * 0.125f : -1e9f;
            sc[t8][1][i] = okB ? sB[i] * 0.125f : -1e9f;
        }
    }

    // exact row max, exp, row sum (per row i, reduce over 16 r-lanes once)
    float mx[4], ls[4];
    #pragma unroll
    for (int i = 0; i < 4; ++i) {
        float t = -1e30f;
        #pragma unroll
        for (int t8 = 0; t8 < 8; ++t8) {
            t = fmaxf(t, sc[t8][0][i]);
            t = fmaxf(t, sc[t8][1][i]);
        }
        t = fmaxf(t, __shfl_xor(t, 1));
        t = fmaxf(t, __shfl_xor(t, 2));
        t = fmaxf(t, __shfl_xor(t, 4));
        t = fmaxf(t, __shfl_xor(t, 8));
        mx[i] = t;
        float sum = 0.f;
        #pragma unroll
        for (int t8 = 0; t8 < 8; ++t8) {
            float e0 = __expf(sc[t8][0][i] - t);
            float e1 = __expf(sc[t8][1][i] - t);
            sc[t8][0][i] = e0;
            sc[t8][1][i] = e1;
            sum += e0 + e1;
        }
        sum += __shfl_xor(sum, 1);
        sum += __shfl_xor(sum, 2);
        sum += __shfl_xor(sum, 4);
        sum += __shfl_xor(sum, 8);
        ls[i] = sum;
    }

    // pass 2: PV (P from registers through per-wave LDS bounce)
    f32x4 o[4] = {};
    #pragma unroll
    for (int t8 = 0; t8 < 8; ++t8) {
        int kt = t8 * 32;
        #pragma unroll
        for (int i = 0; i < 4; ++i) {
            pw[(q * 4 + i) * 32 + r] = (bf16)sc[t8][0][i];
            pw[(q * 4 + i) * 32 + 16 + r] = (bf16)sc[t8][1][i];
        }
        // same-wave LDS write->read: DS ops execute in order within a wave
        bf16x8 pf = *reinterpret_cast<const bf16x8*>(&pw[r * 32 + q * 8]);
        #pragma unroll
        for (int t = 0; t < 4; ++t) {
            bf16x8 vf = *reinterpret_cast<const bf16x8*>(vbase + (size_t)(t * 16 + r) * 1024 + kt + q * 8);
            o[t] = __builtin_amdgcn_mfma_f32_16x16x32_bf16(pf, vf, o[t], 0, 0, 0);
        }
    }

    // per-slice results to LDS
    #pragma unroll
    for (int t = 0; t < 4; ++t)
        #pragma unroll
        for (int i = 0; i < 4; ++i)
            obuf[s][q * 4 + i][t * 16 + r] = o[t][i];
    if (r == 0) {
        #pragma unroll
        for (int i = 0; i < 4; ++i) {
            lbuf[s][q * 4 + i] = ls[i];
            mbuf[s][q * 4 + i] = mx[i];
        }
    }
    __syncthreads();

    // exact combine: thread t -> row t>>4, cols (t&15)*4..+3
    int row = threadIdx.x >> 4, cg = threadIdx.x & 15;
    float m0 = mbuf[0][row], m1 = mbuf[1][row], m2 = mbuf[2][row], m3 = mbuf[3][row];
    float mt = fmaxf(fmaxf(m0, m1), fmaxf(m2, m3));
    float f0 = __expf(m0 - mt), f1 = __expf(m1 - mt);
    float f2 = __expf(m2 - mt), f3 = __expf(m3 - mt);
    float l = lbuf[0][row] * f0 + lbuf[1][row] * f1 + lbuf[2][row] * f2 + lbuf[3][row] * f3;
    f32x4 a0 = *reinterpret_cast<const f32x4*>(&obuf[0][row][cg * 4]);
    f32x4 a1 = *reinterpret_cast<const f32x4*>(&obuf[1][row][cg * 4]);
    f32x4 a2 = *reinterpret_cast<const f32x4*>(&obuf[2][row][cg * 4]);
    f32x4 a3 = *reinterpret_cast<const f32x4*>(&obuf[3][row][cg * 4]);
    float inv = 1.0f / l;
    bf16x4 ov;
    #pragma unroll
    for (int j = 0; j < 4; ++j)
        ov[j] = (bf16)((a0[j] * f0 + a1[j] * f1 + a2[j] * f2 + a3[j] * f3) * inv);
    *reinterpret_cast<bf16x4*>(out + (size_t)(b * 1024 + qt * 16 + row) * DM + h * 64 + cg * 4) = ov;
}

// ---------------------------------------------------------------------------
extern "C" void kernel_launch(void* const* d_in, const int* in_sizes, int n_in,
                              void* d_out, int out_size, void* d_ws, size_t ws_size,
                              hipStream_t stream) {
    const float* x      = (const float*)d_in[0];
    const int*   mask   = (const int*)  d_in[1];
    const float* w_q    = (const float*)d_in[2];
    const float* w_k    = (const float*)d_in[3];
    const float* w_v    = (const float*)d_in[4];
    const float* w_o    = (const float*)d_in[5];
    const float* alpha1 = (const float*)d_in[6];
    const float* beta1  = (const float*)d_in[7];
    const float* alpha2 = (const float*)d_in[8];
    const float* beta2  = (const float*)d_in[9];
    const float* fc1_w  = (const float*)d_in[10];
    const float* fc1_b  = (const float*)d_in[11];
    const float* fc2_w  = (const float*)d_in[12];
    const float* fc2_b  = (const float*)d_in[13];
    float* out = (float*)d_out;

    char* ws = (char*)d_ws;
    const size_t MB = 1024 * 1024;
    bf16*  wqkv_b = (bf16*)(ws +  0 * MB);   // 6 MB  (dead after QKV gemm)
    bf16*  wo_b   = (bf16*)(ws +  6 * MB);   // 2 MB  (dead after o-proj)
    bf16*  f1w_b  = (bf16*)(ws +  8 * MB);   // 8 MB  (dead after fc1)
    bf16*  f2w_b  = (bf16*)(ws + 16 * MB);   // 8 MB
    bf16*  xn     = (bf16*)(ws + 24 * MB);   // 4 MB
    bf16*  qkvb   = (bf16*)(ws + 28 * MB);   // 12 MB (dead after attn)
    bf16*  vtb    = (bf16*)(ws + 40 * MB);   // 4 MB  (dead after attn)
    bf16*  attnb  = (bf16*)(ws + 44 * MB);   // 4 MB  (dead after o-proj)
    float* x2     = (float*)(ws + 48 * MB);  // 8 MB
    float* po     = (float*)(ws + 28 * MB);  // 16 MB o-proj partials (over qkv/vt)
    bf16*  hb     = (bf16*)(ws + 28 * MB);   // 16 MB fc1 out (over po)
    float* pf2    = (float*)(ws +  0 * MB);  // 16 MB fc2 partials (over dead weights)

    // 1) all weights -> bf16
    f2b_all_kernel<<<12288, 256, 0, stream>>>(
        (const float4*)w_q, (const float4*)w_k, (const float4*)w_v, (const float4*)w_o,
        (const float4*)fc1_w, (const float4*)fc2_w,
        (bf16x4*)wqkv_b, (bf16x4*)wo_b, (bf16x4*)f1w_b, (bf16x4*)f2w_b);

    // 2) ln1
    ln_kernel<<<NTOK, 256, 0, stream>>>(x, alpha1, beta1, xn);

    // 3) fused QKV projection
    gemm128<0><<<dim3(QKVN / 128, NTOK / 128, 1), 256, 0, stream>>>(
        xn, wqkv_b, qkvb, nullptr, NTOK, QKVN, DM, DM);

    // 4) V -> (B,H,DK,S)
    transpose_v<<<dim3(32, 2, 32), dim3(32, 32), 0, stream>>>(qkvb, vtb);

    // 5) attention (2048 blocks: one q-tile each, 4 key-slices)
    attn_kernel<<<2048, 256, 0, stream>>>(qkvb, vtb, mask, attnb);

    // 6) o-proj split-K=2 partials
    gemm128<4><<<dim3(DM / 128, NTOK / 128, 2), 256, 0, stream>>>(
        attnb, wo_b, po, nullptr, NTOK, DM, DM, DM / 2);

    // 7) reduce + residual -> x2, fused ln2 -> xn
    reduce_ln_kernel<<<NTOK, 256, 0, stream>>>(po, x, alpha2, beta2, x2, xn);

    // 8) fc1 + bias + relu
    gemm128<1><<<dim3(DFC / 128, NTOK / 128, 1), 256, 0, stream>>>(
        xn, f1w_b, hb, fc1_b, NTOK, DFC, DM, DM);

    // 9) fc2 split-K=2 partials
    gemm128<4><<<dim3(DM / 128, NTOK / 128, 2), 256, 0, stream>>>(
        hb, f2w_b, pf2, nullptr, NTOK, DM, DFC, DFC / 2);

    // 10) reduce + bias + residual -> out
    reduce_out_kernel<<<2048, 256, 0, stream>>>(pf2, fc2_b, x2, out);
}

// Round 6
// 274.293 us; speedup vs baseline: 3.3298x; 1.0965x over previous
//
#include <hip/hip_runtime.h>
#include <hip/hip_bf16.h>

// ---------------------------------------------------------------------------
// EncoderBlock round 6:
//  - attention: flash-style block = 64 q-rows (4 waves x 16), K/V tiles
//    (64 keys) staged in LDS via double-buffered global_load_lds(16B),
//    shared by all 4 waves; exact online softmax (running max);
//    XOR-swizzled K/V/P LDS layouts for conflict-free ds_read_b128.
//    (round 5: per-wave scattered K/V loads -> latency-bound, 66us)
//  - gemm128: BK=64, XOR-swizzled LDS (unchanged from round 5)
// MFMA layouts (verified): A[m=lane&15][k=(lane>>4)*8+j],
//   B[k=(lane>>4)*8+j][n=lane&15], C/D row=(lane>>4)*4+reg, col=lane&15.
// ---------------------------------------------------------------------------

typedef __bf16 bf16;
typedef __attribute__((ext_vector_type(8))) __bf16 bf16x8;
typedef __attribute__((ext_vector_type(4))) __bf16 bf16x4;
typedef __attribute__((ext_vector_type(4))) float f32x4;

#define NTOK 2048
#define DM   1024
#define DFC  4096
#define QKVN 3072

__device__ inline void gl_lds16(const void* g, void* l) {
    __builtin_amdgcn_global_load_lds((const __attribute__((address_space(1))) void*)g,
                                     (__attribute__((address_space(3))) void*)l, 16, 0, 0);
}

// ---------------- all weights fp32 -> bf16, one dispatch --------------------
__global__ __launch_bounds__(256) void f2b_all_kernel(
    const float4* __restrict__ wq, const float4* __restrict__ wk,
    const float4* __restrict__ wv, const float4* __restrict__ wo,
    const float4* __restrict__ f1, const float4* __restrict__ f2,
    bf16x4* __restrict__ oqkv, bf16x4* __restrict__ oo,
    bf16x4* __restrict__ of1, bf16x4* __restrict__ of2) {
    int i = blockIdx.x * 256 + threadIdx.x;
    const int Q = 262144;                        // 1024*1024/4
    float4 v;
    bf16x4* dst;
    if (i < 3 * Q) {
        v = (i < Q) ? wq[i] : (i < 2 * Q) ? wk[i - Q] : wv[i - 2 * Q];
        dst = oqkv + i;
    } else if (i < 4 * Q) {
        v = wo[i - 3 * Q];
        dst = oo + (i - 3 * Q);
    } else if (i < 8 * Q) {
        v = f1[i - 4 * Q];
        dst = of1 + (i - 4 * Q);
    } else {
        v = f2[i - 8 * Q];
        dst = of2 + (i - 8 * Q);
    }
    bf16x4 o;
    o[0] = (bf16)v.x; o[1] = (bf16)v.y; o[2] = (bf16)v.z; o[3] = (bf16)v.w;
    *dst = o;
}

// ---------------- LayerNorm (torch: std ddof=1, /(std+eps)) ----------------
__device__ inline void ln_row(float4 v, const float* alpha, const float* beta,
                              bf16* outrow, int t) {
    float s  = v.x + v.y + v.z + v.w;
    float ss = v.x * v.x + v.y * v.y + v.z * v.z + v.w * v.w;
    __shared__ float red[8];
    int lane = t & 63, wv = t >> 6;
    #pragma unroll
    for (int o = 32; o > 0; o >>= 1) {
        s  += __shfl_down(s, o);
        ss += __shfl_down(ss, o);
    }
    if (lane == 0) { red[wv] = s; red[4 + wv] = ss; }
    __syncthreads();
    float S  = red[0] + red[1] + red[2] + red[3];
    float SS = red[4] + red[5] + red[6] + red[7];
    float mean = S * (1.0f / 1024.0f);
    float var  = (SS - S * mean) * (1.0f / 1023.0f);
    var = var < 0.f ? 0.f : var;
    float inv = 1.0f / (sqrtf(var) + 1e-6f);
    float4 a4 = reinterpret_cast<const float4*>(alpha)[t];
    float4 b4 = reinterpret_cast<const float4*>(beta)[t];
    bf16x4 o4;
    o4[0] = (bf16)(a4.x * (v.x - mean) * inv + b4.x);
    o4[1] = (bf16)(a4.y * (v.y - mean) * inv + b4.y);
    o4[2] = (bf16)(a4.z * (v.z - mean) * inv + b4.z);
    o4[3] = (bf16)(a4.w * (v.w - mean) * inv + b4.w);
    reinterpret_cast<bf16x4*>(outrow)[t] = o4;
}

__global__ __launch_bounds__(256) void ln_kernel(const float* __restrict__ x,
                                                 const float* __restrict__ alpha,
                                                 const float* __restrict__ beta,
                                                 bf16* __restrict__ out) {
    int row = blockIdx.x, t = threadIdx.x;
    float4 v = reinterpret_cast<const float4*>(x + (size_t)row * DM)[t];
    ln_row(v, alpha, beta, out + (size_t)row * DM, t);
}

// ---- o-proj split-K reduce + residual -> x2, fused ln2 -> xn (block=row) ---
__global__ __launch_bounds__(256) void reduce_ln_kernel(const float* __restrict__ p,
                                                        const float* __restrict__ resid,
                                                        const float* __restrict__ alpha,
                                                        const float* __restrict__ beta,
                                                        float* __restrict__ x2,
                                                        bf16* __restrict__ xn) {
    int row = blockIdx.x, t = threadIdx.x;
    size_t i4 = (size_t)row * 256 + t;
    float4 a = reinterpret_cast<const float4*>(p)[i4];
    float4 b = reinterpret_cast<const float4*>(p)[i4 + 524288];
    float4 r = reinterpret_cast<const float4*>(resid)[i4];
    float4 v;
    v.x = a.x + b.x + r.x; v.y = a.y + b.y + r.y;
    v.z = a.z + b.z + r.z; v.w = a.w + b.w + r.w;
    reinterpret_cast<float4*>(x2)[i4] = v;
    ln_row(v, alpha, beta, xn + (size_t)row * DM, t);
}

// ---- fc2 split-K reduce + bias + residual -> d_out (fp32) ------------------
__global__ __launch_bounds__(256) void reduce_out_kernel(const float* __restrict__ p,
                                                         const float* __restrict__ bias,
                                                         const float* __restrict__ x2,
                                                         float* __restrict__ out) {
    size_t i4 = (size_t)blockIdx.x * 256 + threadIdx.x;
    float4 a = reinterpret_cast<const float4*>(p)[i4];
    float4 b = reinterpret_cast<const float4*>(p)[i4 + 524288];
    float4 r = reinterpret_cast<const float4*>(x2)[i4];
    float4 bi = reinterpret_cast<const float4*>(bias)[i4 & 255];
    float4 o;
    o.x = a.x + b.x + r.x + bi.x; o.y = a.y + b.y + r.y + bi.y;
    o.z = a.z + b.z + r.z + bi.z; o.w = a.w + b.w + r.w + bi.w;
    reinterpret_cast<float4*>(out)[i4] = o;
}

// ---------------- GEMM: 128x128 tile, BK=64, swizzled LDS -------------------
// LDS layout: 8-elem chunk c of row m stored at pos = c ^ (m&7); row stride
// 128B -> ds_read_b128 is 2-way-bank (free). gl_lds dest stays lane*16B.
// EPI: 0 = store bf16; 1 = relu(v+bias) bf16; 4 = fp32 partial at z*M*N
template <int EPI>
__global__ __launch_bounds__(256) void gemm128(const bf16* __restrict__ A,
                                               const bf16* __restrict__ Bt,
                                               void* __restrict__ outp,
                                               const float* __restrict__ bias,
                                               int M, int N, int K, int kslice) {
    __shared__ bf16 As[128 * 64];   // 16 KB
    __shared__ bf16 Bs[128 * 64];   // 16 KB
    int tid = threadIdx.x;
    int lane = tid & 63, wave = tid >> 6;
    int q = lane >> 4, r = lane & 15;
    int wm = wave >> 1, wn = wave & 1;
    int m0 = blockIdx.y * 128, n0 = blockIdx.x * 128;
    int kbeg = blockIdx.z * kslice, kend = kbeg + kslice;
    f32x4 acc[4][4] = {};

    int srow = tid >> 3;
    int csrc = (tid & 7) ^ (srow & 7);
    const bf16* agp = A  + (size_t)(m0 + srow) * K + csrc * 8;
    const bf16* bgp = Bt + (size_t)(n0 + srow) * K + csrc * 8;
    bf16* alp = As + tid * 8;
    bf16* blp = Bs + tid * 8;

    int rsw = (r & 7);
    int co0 = ((q ^ rsw) * 8);
    int co1 = co0 ^ 32;
    const bf16* ara = As + (wm * 64 + r) * 64;
    const bf16* brb = Bs + (wn * 64 + r) * 64;

    for (int k0 = kbeg; k0 < kend; k0 += 64) {
        #pragma unroll
        for (int j = 0; j < 4; ++j) {
            gl_lds16(agp + (size_t)j * 32 * K + k0, alp + j * 2048);
            gl_lds16(bgp + (size_t)j * 32 * K + k0, blp + j * 2048);
        }
        __syncthreads();
        #pragma unroll
        for (int half = 0; half < 2; ++half) {
            int co = half ? co1 : co0;
            bf16x8 af[4], bfv[4];
            #pragma unroll
            for (int t = 0; t < 4; ++t)
                af[t] = *reinterpret_cast<const bf16x8*>(ara + t * 1024 + co);
            #pragma unroll
            for (int u = 0; u < 4; ++u)
                bfv[u] = *reinterpret_cast<const bf16x8*>(brb + u * 1024 + co);
            #pragma unroll
            for (int t = 0; t < 4; ++t)
                #pragma unroll
                for (int u = 0; u < 4; ++u)
                    acc[t][u] = __builtin_amdgcn_mfma_f32_16x16x32_bf16(af[t], bfv[u], acc[t][u], 0, 0, 0);
        }
        __syncthreads();
    }

    size_t zoff = (size_t)blockIdx.z * M * N;
    #pragma unroll
    for (int t = 0; t < 4; ++t) {
        #pragma unroll
        for (int u = 0; u < 4; ++u) {
            #pragma unroll
            for (int i = 0; i < 4; ++i) {
                int mm = m0 + wm * 64 + t * 16 + q * 4 + i;
                int nn = n0 + wn * 64 + u * 16 + r;
                size_t idx = (size_t)mm * N + nn;
                float v = acc[t][u][i];
                if (EPI == 0) {
                    ((bf16*)outp)[idx] = (bf16)v;
                } else if (EPI == 1) {
                    v += bias[nn];
                    ((bf16*)outp)[idx] = (bf16)(v > 0.f ? v : 0.f);
                } else {
                    ((float*)outp)[zoff + idx] = v;
                }
            }
        }
    }
}

// ---------------- V transpose: qkv[:, 2048+h*64+d] -> Vt (B,H,DK,S) ---------
__global__ void transpose_v(const bf16* __restrict__ qkv, bf16* __restrict__ vt) {
    __shared__ bf16 tile[32][33];
    int bh = blockIdx.z;
    int b = bh >> 4, h = bh & 15;
    int s0 = blockIdx.x * 32;
    int d0 = blockIdx.y * 32;
    int tx = threadIdx.x, ty = threadIdx.y;
    tile[ty][tx] = qkv[(size_t)(b * 1024 + s0 + ty) * QKVN + 2048 + h * 64 + d0 + tx];
    __syncthreads();
    vt[(size_t)(bh * 64 + d0 + ty) * 1024 + s0 + tx] = tile[tx][ty];
}

// ---------------- flash attention: 64 q-rows/block, LDS-staged K/V ----------
// grid 512 = (b, h, qb); 4 waves = 4 q-tiles of 16 rows sharing K/V tiles.
// Per 64-key tile: K (64x64, [key][dk]) + V (64x64, [dk][key], from Vt) staged
// via global_load_lds, double-buffered, prefetched one tile ahead.
// All LDS tiles XOR-swizzled: chunk c of row m at pos c^(m&7) (rows = 128 B).
// Online softmax with exact running max (numerics proven rounds 2/3/5).
__global__ __launch_bounds__(256) void attn_kernel(const bf16* __restrict__ qkv,
                                                   const bf16* __restrict__ Vt,
                                                   const int* __restrict__ mask,
                                                   bf16* __restrict__ out) {
    __shared__ bf16 Ks[2][4096];     // 16 KB
    __shared__ bf16 Vs[2][4096];     // 16 KB
    __shared__ bf16 pbuf[4][1024];   // 8 KB (per-wave P bounce, swizzled)
    __shared__ float msk[1024];      // 4 KB additive mask bias
    int tid = threadIdx.x;
    int lane = tid & 63, w = tid >> 6;
    int q = lane >> 4, r = lane & 15;
    int id = blockIdx.x;
    int qb = id & 15, h = (id >> 4) & 15, b = id >> 8;

    // mask -> LDS additive bias (0 or -1e9)
    {
        int4 mi = reinterpret_cast<const int4*>(mask + b * 1024)[tid];
        msk[tid * 4 + 0] = mi.x ? 0.f : -1e9f;
        msk[tid * 4 + 1] = mi.y ? 0.f : -1e9f;
        msk[tid * 4 + 2] = mi.z ? 0.f : -1e9f;
        msk[tid * 4 + 3] = mi.w ? 0.f : -1e9f;
    }

    // Q fragments (held in regs): rows qb*64 + w*16 + r
    const bf16* qrow = qkv + (size_t)(b * 1024 + qb * 64 + w * 16 + r) * QKVN + h * 64 + q * 8;
    bf16x8 qf0 = *reinterpret_cast<const bf16x8*>(qrow);
    bf16x8 qf1 = *reinterpret_cast<const bf16x8*>(qrow + 32);

    // staging: thread tid owns LDS 16B slots tid and tid+256 of each tile.
    // slot c: row = c>>3, pos = c&7 -> source chunk = pos ^ (row&7).
    int csw = (tid & 7) ^ ((tid >> 3) & 7);
    const bf16* kg0 = qkv + (size_t)(b * 1024 + (tid >> 3)) * QKVN + 1024 + h * 64 + csw * 8;
    const bf16* kg1 = kg0 + (size_t)32 * QKVN;
    const bf16* vg0 = Vt + (size_t)((b * 16 + h) * 64 + (tid >> 3)) * 1024 + csw * 8;
    const bf16* vg1 = vg0 + 32 * 1024;
    bf16* kld = &Ks[0][tid * 8];
    bf16* vld = &Vs[0][tid * 8];

    int co0 = (q ^ (r & 7)) * 8;     // K fragment chunk q at pos q^(r&7)
    bf16* pw = pbuf[w];

    float m[4] = {-1e30f, -1e30f, -1e30f, -1e30f};
    float l[4] = {0.f, 0.f, 0.f, 0.f};
    f32x4 o[4] = {};

    // prefetch tile 0
    gl_lds16(kg0, kld);
    gl_lds16(kg1, kld + 2048);
    gl_lds16(vg0, vld);
    gl_lds16(vg1, vld + 2048);

    for (int t = 0; t < 16; ++t) {
        __syncthreads();                       // drains vmcnt -> buf[t&1] ready
        if (t < 15) {                          // prefetch t+1 into other buffer
            int ktn = (t + 1) * 64;
            int bo = ((t + 1) & 1) * 4096;
            gl_lds16(kg0 + (size_t)ktn * QKVN, kld + bo);
            gl_lds16(kg1 + (size_t)ktn * QKVN, kld + bo + 2048);
            gl_lds16(vg0 + ktn, vld + bo);
            gl_lds16(vg1 + ktn, vld + bo + 2048);
        }
        const bf16* Kb = Ks[t & 1];
        const bf16* Vb = Vs[t & 1];
        int kt = t * 64;

        // QK^T for 4 key-subtiles -> s[ks] (row q*4+i, col ks*16+r)
        f32x4 s[4];
        #pragma unroll
        for (int ks = 0; ks < 4; ++ks) {
            bf16x8 kf0 = *reinterpret_cast<const bf16x8*>(&Kb[(ks * 16 + r) * 64 + co0]);
            bf16x8 kf1 = *reinterpret_cast<const bf16x8*>(&Kb[(ks * 16 + r) * 64 + (co0 ^ 32)]);
            f32x4 a = {};
            a = __builtin_amdgcn_mfma_f32_16x16x32_bf16(qf0, kf0, a, 0, 0, 0);
            a = __builtin_amdgcn_mfma_f32_16x16x32_bf16(qf1, kf1, a, 0, 0, 0);
            float mb = msk[kt + ks * 16 + r];
            #pragma unroll
            for (int i = 0; i < 4; ++i) s[ks][i] = fmaf(a[i], 0.125f, mb);
        }
        // online softmax, exact running max
        float alpha[4];
        #pragma unroll
        for (int i = 0; i < 4; ++i) {
            float t2 = fmaxf(fmaxf(s[0][i], s[1][i]), fmaxf(s[2][i], s[3][i]));
            t2 = fmaxf(t2, __shfl_xor(t2, 1));
            t2 = fmaxf(t2, __shfl_xor(t2, 2));
            t2 = fmaxf(t2, __shfl_xor(t2, 4));
            t2 = fmaxf(t2, __shfl_xor(t2, 8));
            float mn = fmaxf(m[i], t2);
            alpha[i] = __expf(m[i] - mn);
            m[i] = mn;
        }
        #pragma unroll
        for (int i = 0; i < 4; ++i) {
            float e0 = __expf(s[0][i] - m[i]);
            float e1 = __expf(s[1][i] - m[i]);
            float e2 = __expf(s[2][i] - m[i]);
            float e3 = __expf(s[3][i] - m[i]);
            s[0][i] = e0; s[1][i] = e1; s[2][i] = e2; s[3][i] = e3;
            float rs = (e0 + e1) + (e2 + e3);
            rs += __shfl_xor(rs, 1);
            rs += __shfl_xor(rs, 2);
            rs += __shfl_xor(rs, 4);
            rs += __shfl_xor(rs, 8);
            l[i] = l[i] * alpha[i] + rs;
        }
        #pragma unroll
        for (int nt = 0; nt < 4; ++nt)
            #pragma unroll
            for (int i = 0; i < 4; ++i) o[nt][i] *= alpha[i];
        // P -> per-wave LDS (swizzled): elem (row mr, col ks*16+r)
        #pragma unroll
        for (int ks = 0; ks < 4; ++ks) {
            int kc = ks * 2 + (r >> 3);
            #pragma unroll
            for (int i = 0; i < 4; ++i) {
                int mr = q * 4 + i;
                pw[mr * 64 + ((kc ^ (mr & 7)) * 8) + (r & 7)] = (bf16)s[ks][i];
            }
        }
        // PV: 2 k-steps of 32 keys (same-wave DS in-order, no barrier)
        #pragma unroll
        for (int ks2 = 0; ks2 < 2; ++ks2) {
            int vpo = (((ks2 * 4 + q) ^ (r & 7)) * 8);
            bf16x8 pf = *reinterpret_cast<const bf16x8*>(&pw[r * 64 + vpo]);
            #pragma unroll
            for (int nt = 0; nt < 4; ++nt) {
                bf16x8 vf = *reinterpret_cast<const bf16x8*>(&Vb[(nt * 16 + r) * 64 + vpo]);
                o[nt] = __builtin_amdgcn_mfma_f32_16x16x32_bf16(pf, vf, o[nt], 0, 0, 0);
            }
        }
    }

    float inv[4];
    #pragma unroll
    for (int i = 0; i < 4; ++i) inv[i] = 1.0f / l[i];
    #pragma unroll
    for (int nt = 0; nt < 4; ++nt)
        #pragma unroll
        for (int i = 0; i < 4; ++i)
            out[(size_t)(b * 1024 + qb * 64 + w * 16 + q * 4 + i) * DM + h * 64 + nt * 16 + r] =
                (bf16)(o[nt][i] * inv[i]);
}

// ---------------------------------------------------------------------------
extern "C" void kernel_launch(void* const* d_in, const int* in_sizes, int n_in,
                              void* d_out, int out_size, void* d_ws, size_t ws_size,
                              hipStream_t stream) {
    const float* x      = (const float*)d_in[0];
    const int*   mask   = (const int*)  d_in[1];
    const float* w_q    = (const float*)d_in[2];
    const float* w_k    = (const float*)d_in[3];
    const float* w_v    = (const float*)d_in[4];
    const float* w_o    = (const float*)d_in[5];
    const float* alpha1 = (const float*)d_in[6];
    const float* beta1  = (const float*)d_in[7];
    const float* alpha2 = (const float*)d_in[8];
    const float* beta2  = (const float*)d_in[9];
    const float* fc1_w  = (const float*)d_in[10];
    const float* fc1_b  = (const float*)d_in[11];
    const float* fc2_w  = (const float*)d_in[12];
    const float* fc2_b  = (const float*)d_in[13];
    float* out = (float*)d_out;

    char* ws = (char*)d_ws;
    const size_t MB = 1024 * 1024;
    bf16*  wqkv_b = (bf16*)(ws +  0 * MB);   // 6 MB  (dead after QKV gemm)
    bf16*  wo_b   = (bf16*)(ws +  6 * MB);   // 2 MB  (dead after o-proj)
    bf16*  f1w_b  = (bf16*)(ws +  8 * MB);   // 8 MB  (dead after fc1)
    bf16*  f2w_b  = (bf16*)(ws + 16 * MB);   // 8 MB
    bf16*  xn     = (bf16*)(ws + 24 * MB);   // 4 MB
    bf16*  qkvb   = (bf16*)(ws + 28 * MB);   // 12 MB (dead after attn)
    bf16*  vtb    = (bf16*)(ws + 40 * MB);   // 4 MB  (dead after attn)
    bf16*  attnb  = (bf16*)(ws + 44 * MB);   // 4 MB  (dead after o-proj)
    float* x2     = (float*)(ws + 48 * MB);  // 8 MB
    float* po     = (float*)(ws + 28 * MB);  // 16 MB o-proj partials (over qkv/vt)
    bf16*  hb     = (bf16*)(ws + 28 * MB);   // 16 MB fc1 out (over po)
    float* pf2    = (float*)(ws +  0 * MB);  // 16 MB fc2 partials (over dead weights)

    // 1) all weights -> bf16
    f2b_all_kernel<<<12288, 256, 0, stream>>>(
        (const float4*)w_q, (const float4*)w_k, (const float4*)w_v, (const float4*)w_o,
        (const float4*)fc1_w, (const float4*)fc2_w,
        (bf16x4*)wqkv_b, (bf16x4*)wo_b, (bf16x4*)f1w_b, (bf16x4*)f2w_b);

    // 2) ln1
    ln_kernel<<<NTOK, 256, 0, stream>>>(x, alpha1, beta1, xn);

    // 3) fused QKV projection
    gemm128<0><<<dim3(QKVN / 128, NTOK / 128, 1), 256, 0, stream>>>(
        xn, wqkv_b, qkvb, nullptr, NTOK, QKVN, DM, DM);

    // 4) V -> (B,H,DK,S)
    transpose_v<<<dim3(32, 2, 32), dim3(32, 32), 0, stream>>>(qkvb, vtb);

    // 5) flash attention (512 blocks: 64 q-rows each)
    attn_kernel<<<512, 256, 0, stream>>>(qkvb, vtb, mask, attnb);

    // 6) o-proj split-K=2 partials
    gemm128<4><<<dim3(DM / 128, NTOK / 128, 2), 256, 0, stream>>>(
        attnb, wo_b, po, nullptr, NTOK, DM, DM, DM / 2);

    // 7) reduce + residual -> x2, fused ln2 -> xn
    reduce_ln_kernel<<<NTOK, 256, 0, stream>>>(po, x, alpha2, beta2, x2, xn);

    // 8) fc1 + bias + relu
    gemm128<1><<<dim3(DFC / 128, NTOK / 128, 1), 256, 0, stream>>>(
        xn, f1w_b, hb, fc1_b, NTOK, DFC, DM, DM);

    // 9) fc2 split-K=2 partials
    gemm128<4><<<dim3(DM / 128, NTOK / 128, 2), 256, 0, stream>>>(
        hb, f2w_b, pf2, nullptr, NTOK, DM, DFC, DFC / 2);

    // 10) reduce + bias + residual -> out
    reduce_out_kernel<<<2048, 256, 0, stream>>>(pf2, fc2_b, x2, out);
}

// Round 7
// 262.719 us; speedup vs baseline: 3.4765x; 1.0441x over previous
//
#include <hip/hip_runtime.h>
#include <hip/hip_bf16.h>

// ---------------------------------------------------------------------------
// EncoderBlock round 7:
//  - gemm128: EXPLICIT DOUBLE-BUFFERED K-loop (barrier -> prefetch next tile
//    into other 32KB buffer -> compute current). One barrier/iter. 64 KB LDS.
//    Rationale: grids are 256-512 blocks (1-2/CU); round-6 single-buffer
//    exposed full load latency at each barrier (MfmaUtil 13.5%, occ 9%).
//  - f2b + ln1 merged into one prep dispatch.
//  - attention / transpose / reduces unchanged (round 6, verified).
// MFMA layouts (verified): A[m=lane&15][k=(lane>>4)*8+j],
//   B[k=(lane>>4)*8+j][n=lane&15], C/D row=(lane>>4)*4+reg, col=lane&15.
// ---------------------------------------------------------------------------

typedef __bf16 bf16;
typedef __attribute__((ext_vector_type(8))) __bf16 bf16x8;
typedef __attribute__((ext_vector_type(4))) __bf16 bf16x4;
typedef __attribute__((ext_vector_type(4))) float f32x4;

#define NTOK 2048
#define DM   1024
#define DFC  4096
#define QKVN 3072

__device__ inline void gl_lds16(const void* g, void* l) {
    __builtin_amdgcn_global_load_lds((const __attribute__((address_space(1))) void*)g,
                                     (__attribute__((address_space(3))) void*)l, 16, 0, 0);
}

// ---------------- LayerNorm row helper (torch: std ddof=1, /(std+eps)) -----
__device__ inline void ln_row(float4 v, const float* alpha, const float* beta,
                              bf16* outrow, int t) {
    float s  = v.x + v.y + v.z + v.w;
    float ss = v.x * v.x + v.y * v.y + v.z * v.z + v.w * v.w;
    __shared__ float red[8];
    int lane = t & 63, wv = t >> 6;
    #pragma unroll
    for (int o = 32; o > 0; o >>= 1) {
        s  += __shfl_down(s, o);
        ss += __shfl_down(ss, o);
    }
    if (lane == 0) { red[wv] = s; red[4 + wv] = ss; }
    __syncthreads();
    float S  = red[0] + red[1] + red[2] + red[3];
    float SS = red[4] + red[5] + red[6] + red[7];
    float mean = S * (1.0f / 1024.0f);
    float var  = (SS - S * mean) * (1.0f / 1023.0f);
    var = var < 0.f ? 0.f : var;
    float inv = 1.0f / (sqrtf(var) + 1e-6f);
    float4 a4 = reinterpret_cast<const float4*>(alpha)[t];
    float4 b4 = reinterpret_cast<const float4*>(beta)[t];
    bf16x4 o4;
    o4[0] = (bf16)(a4.x * (v.x - mean) * inv + b4.x);
    o4[1] = (bf16)(a4.y * (v.y - mean) * inv + b4.y);
    o4[2] = (bf16)(a4.z * (v.z - mean) * inv + b4.z);
    o4[3] = (bf16)(a4.w * (v.w - mean) * inv + b4.w);
    reinterpret_cast<bf16x4*>(outrow)[t] = o4;
}

// ---------------- prep: all weights fp32->bf16 AND ln1, one dispatch --------
__global__ __launch_bounds__(256) void prep_kernel(
    const float4* __restrict__ wq, const float4* __restrict__ wk,
    const float4* __restrict__ wv, const float4* __restrict__ wo,
    const float4* __restrict__ f1, const float4* __restrict__ f2,
    bf16x4* __restrict__ oqkv, bf16x4* __restrict__ oo,
    bf16x4* __restrict__ of1, bf16x4* __restrict__ of2,
    const float* __restrict__ x, const float* __restrict__ alpha1,
    const float* __restrict__ beta1, bf16* __restrict__ xn) {
    int blk = blockIdx.x;
    int t = threadIdx.x;
    if (blk < 12288) {
        int i = blk * 256 + t;
        const int Q = 262144;                        // 1024*1024/4
        float4 v;
        bf16x4* dst;
        if (i < 3 * Q) {
            v = (i < Q) ? wq[i] : (i < 2 * Q) ? wk[i - Q] : wv[i - 2 * Q];
            dst = oqkv + i;
        } else if (i < 4 * Q) {
            v = wo[i - 3 * Q];
            dst = oo + (i - 3 * Q);
        } else if (i < 8 * Q) {
            v = f1[i - 4 * Q];
            dst = of1 + (i - 4 * Q);
        } else {
            v = f2[i - 8 * Q];
            dst = of2 + (i - 8 * Q);
        }
        bf16x4 o;
        o[0] = (bf16)v.x; o[1] = (bf16)v.y; o[2] = (bf16)v.z; o[3] = (bf16)v.w;
        *dst = o;
    } else {
        int row = blk - 12288;
        float4 v = reinterpret_cast<const float4*>(x + (size_t)row * DM)[t];
        ln_row(v, alpha1, beta1, xn + (size_t)row * DM, t);
    }
}

// ---- o-proj split-K reduce + residual -> x2, fused ln2 -> xn (block=row) ---
__global__ __launch_bounds__(256) void reduce_ln_kernel(const float* __restrict__ p,
                                                        const float* __restrict__ resid,
                                                        const float* __restrict__ alpha,
                                                        const float* __restrict__ beta,
                                                        float* __restrict__ x2,
                                                        bf16* __restrict__ xn) {
    int row = blockIdx.x, t = threadIdx.x;
    size_t i4 = (size_t)row * 256 + t;
    float4 a = reinterpret_cast<const float4*>(p)[i4];
    float4 b = reinterpret_cast<const float4*>(p)[i4 + 524288];
    float4 r = reinterpret_cast<const float4*>(resid)[i4];
    float4 v;
    v.x = a.x + b.x + r.x; v.y = a.y + b.y + r.y;
    v.z = a.z + b.z + r.z; v.w = a.w + b.w + r.w;
    reinterpret_cast<float4*>(x2)[i4] = v;
    ln_row(v, alpha, beta, xn + (size_t)row * DM, t);
}

// ---- fc2 split-K reduce + bias + residual -> d_out (fp32) ------------------
__global__ __launch_bounds__(256) void reduce_out_kernel(const float* __restrict__ p,
                                                         const float* __restrict__ bias,
                                                         const float* __restrict__ x2,
                                                         float* __restrict__ out) {
    size_t i4 = (size_t)blockIdx.x * 256 + threadIdx.x;
    float4 a = reinterpret_cast<const float4*>(p)[i4];
    float4 b = reinterpret_cast<const float4*>(p)[i4 + 524288];
    float4 r = reinterpret_cast<const float4*>(x2)[i4];
    float4 bi = reinterpret_cast<const float4*>(bias)[i4 & 255];
    float4 o;
    o.x = a.x + b.x + r.x + bi.x; o.y = a.y + b.y + r.y + bi.y;
    o.z = a.z + b.z + r.z + bi.z; o.w = a.w + b.w + r.w + bi.w;
    reinterpret_cast<float4*>(out)[i4] = o;
}

// ---------------- GEMM: 128x128 tile, BK=64, swizzled LDS, DOUBLE-BUFFERED --
// LDS layout: 8-elem chunk c of row m stored at pos = c ^ (m&7); row stride
// 128B -> ds_read_b128 is 2-way-bank (free). gl_lds dest stays lane*16B.
// K-loop: barrier -> prefetch(it+1) into other buffer -> compute(it).
// The barrier at top of it+1 drains prefetch(it+1), which had all of
// compute(it) to fly -> exposed latency ~ max(0, mem_lat - compute).
// EPI: 0 = store bf16; 1 = relu(v+bias) bf16; 4 = fp32 partial at z*M*N
template <int EPI>
__global__ __launch_bounds__(256) void gemm128(const bf16* __restrict__ A,
                                               const bf16* __restrict__ Bt,
                                               void* __restrict__ outp,
                                               const float* __restrict__ bias,
                                               int M, int N, int K, int kslice) {
    __shared__ bf16 As[2][128 * 64];   // 32 KB
    __shared__ bf16 Bs[2][128 * 64];   // 32 KB
    int tid = threadIdx.x;
    int lane = tid & 63, wave = tid >> 6;
    int q = lane >> 4, r = lane & 15;
    int wm = wave >> 1, wn = wave & 1;
    int m0 = blockIdx.y * 128, n0 = blockIdx.x * 128;
    int kbeg = blockIdx.z * kslice;
    int nit = kslice / 64;
    f32x4 acc[4][4] = {};

    int srow = tid >> 3;
    int csrc = (tid & 7) ^ (srow & 7);
    const bf16* agp = A  + (size_t)(m0 + srow) * K + kbeg + csrc * 8;
    const bf16* bgp = Bt + (size_t)(n0 + srow) * K + kbeg + csrc * 8;

    int rsw = (r & 7);
    int co0 = ((q ^ rsw) * 8);
    int co1 = co0 ^ 32;
    int aoff = (wm * 64 + r) * 64;
    int boff = (wn * 64 + r) * 64;

    auto stage = [&](int it, int b) {
        int k0 = it * 64;
        #pragma unroll
        for (int j = 0; j < 4; ++j) {
            gl_lds16(agp + (size_t)j * 32 * K + k0, &As[b][tid * 8 + j * 2048]);
            gl_lds16(bgp + (size_t)j * 32 * K + k0, &Bs[b][tid * 8 + j * 2048]);
        }
    };

    stage(0, 0);
    for (int it = 0; it < nit; ++it) {
        __syncthreads();                       // drains stage(it) (vmcnt 0)
        if (it + 1 < nit) stage(it + 1, (it + 1) & 1);
        const bf16* Ab = &As[it & 1][aoff];
        const bf16* Bb = &Bs[it & 1][boff];
        #pragma unroll
        for (int half = 0; half < 2; ++half) {
            int co = half ? co1 : co0;
            bf16x8 af[4], bfv[4];
            #pragma unroll
            for (int t = 0; t < 4; ++t)
                af[t] = *reinterpret_cast<const bf16x8*>(Ab + t * 1024 + co);
            #pragma unroll
            for (int u = 0; u < 4; ++u)
                bfv[u] = *reinterpret_cast<const bf16x8*>(Bb + u * 1024 + co);
            #pragma unroll
            for (int t = 0; t < 4; ++t)
                #pragma unroll
                for (int u = 0; u < 4; ++u)
                    acc[t][u] = __builtin_amdgcn_mfma_f32_16x16x32_bf16(af[t], bfv[u], acc[t][u], 0, 0, 0);
        }
    }

    size_t zoff = (size_t)blockIdx.z * M * N;
    #pragma unroll
    for (int t = 0; t < 4; ++t) {
        #pragma unroll
        for (int u = 0; u < 4; ++u) {
            #pragma unroll
            for (int i = 0; i < 4; ++i) {
                int mm = m0 + wm * 64 + t * 16 + q * 4 + i;
                int nn = n0 + wn * 64 + u * 16 + r;
                size_t idx = (size_t)mm * N + nn;
                float v = acc[t][u][i];
                if (EPI == 0) {
                    ((bf16*)outp)[idx] = (bf16)v;
                } else if (EPI == 1) {
                    v += bias[nn];
                    ((bf16*)outp)[idx] = (bf16)(v > 0.f ? v : 0.f);
                } else {
                    ((float*)outp)[zoff + idx] = v;
                }
            }
        }
    }
}

// ---------------- V transpose: qkv[:, 2048+h*64+d] -> Vt (B,H,DK,S) ---------
__global__ void transpose_v(const bf16* __restrict__ qkv, bf16* __restrict__ vt) {
    __shared__ bf16 tile[32][33];
    int bh = blockIdx.z;
    int b = bh >> 4, h = bh & 15;
    int s0 = blockIdx.x * 32;
    int d0 = blockIdx.y * 32;
    int tx = threadIdx.x, ty = threadIdx.y;
    tile[ty][tx] = qkv[(size_t)(b * 1024 + s0 + ty) * QKVN + 2048 + h * 64 + d0 + tx];
    __syncthreads();
    vt[(size_t)(bh * 64 + d0 + ty) * 1024 + s0 + tx] = tile[tx][ty];
}

// ---------------- flash attention: 64 q-rows/block, LDS-staged K/V ----------
__global__ __launch_bounds__(256) void attn_kernel(const bf16* __restrict__ qkv,
                                                   const bf16* __restrict__ Vt,
                                                   const int* __restrict__ mask,
                                                   bf16* __restrict__ out) {
    __shared__ bf16 Ks[2][4096];     // 16 KB
    __shared__ bf16 Vs[2][4096];     // 16 KB
    __shared__ bf16 pbuf[4][1024];   // 8 KB (per-wave P bounce, swizzled)
    __shared__ float msk[1024];      // 4 KB additive mask bias
    int tid = threadIdx.x;
    int lane = tid & 63, w = tid >> 6;
    int q = lane >> 4, r = lane & 15;
    int id = blockIdx.x;
    int qb = id & 15, h = (id >> 4) & 15, b = id >> 8;

    {
        int4 mi = reinterpret_cast<const int4*>(mask + b * 1024)[tid];
        msk[tid * 4 + 0] = mi.x ? 0.f : -1e9f;
        msk[tid * 4 + 1] = mi.y ? 0.f : -1e9f;
        msk[tid * 4 + 2] = mi.z ? 0.f : -1e9f;
        msk[tid * 4 + 3] = mi.w ? 0.f : -1e9f;
    }

    const bf16* qrow = qkv + (size_t)(b * 1024 + qb * 64 + w * 16 + r) * QKVN + h * 64 + q * 8;
    bf16x8 qf0 = *reinterpret_cast<const bf16x8*>(qrow);
    bf16x8 qf1 = *reinterpret_cast<const bf16x8*>(qrow + 32);

    int csw = (tid & 7) ^ ((tid >> 3) & 7);
    const bf16* kg0 = qkv + (size_t)(b * 1024 + (tid >> 3)) * QKVN + 1024 + h * 64 + csw * 8;
    const bf16* kg1 = kg0 + (size_t)32 * QKVN;
    const bf16* vg0 = Vt + (size_t)((b * 16 + h) * 64 + (tid >> 3)) * 1024 + csw * 8;
    const bf16* vg1 = vg0 + 32 * 1024;
    bf16* kld = &Ks[0][tid * 8];
    bf16* vld = &Vs[0][tid * 8];

    int co0 = (q ^ (r & 7)) * 8;
    bf16* pw = pbuf[w];

    float m[4] = {-1e30f, -1e30f, -1e30f, -1e30f};
    float l[4] = {0.f, 0.f, 0.f, 0.f};
    f32x4 o[4] = {};

    gl_lds16(kg0, kld);
    gl_lds16(kg1, kld + 2048);
    gl_lds16(vg0, vld);
    gl_lds16(vg1, vld + 2048);

    for (int t = 0; t < 16; ++t) {
        __syncthreads();
        if (t < 15) {
            int ktn = (t + 1) * 64;
            int bo = ((t + 1) & 1) * 4096;
            gl_lds16(kg0 + (size_t)ktn * QKVN, kld + bo);
            gl_lds16(kg1 + (size_t)ktn * QKVN, kld + bo + 2048);
            gl_lds16(vg0 + ktn, vld + bo);
            gl_lds16(vg1 + ktn, vld + bo + 2048);
        }
        const bf16* Kb = Ks[t & 1];
        const bf16* Vb = Vs[t & 1];
        int kt = t * 64;

        f32x4 s[4];
        #pragma unroll
        for (int ks = 0; ks < 4; ++ks) {
            bf16x8 kf0 = *reinterpret_cast<const bf16x8*>(&Kb[(ks * 16 + r) * 64 + co0]);
            bf16x8 kf1 = *reinterpret_cast<const bf16x8*>(&Kb[(ks * 16 + r) * 64 + (co0 ^ 32)]);
            f32x4 a = {};
            a = __builtin_amdgcn_mfma_f32_16x16x32_bf16(qf0, kf0, a, 0, 0, 0);
            a = __builtin_amdgcn_mfma_f32_16x16x32_bf16(qf1, kf1, a, 0, 0, 0);
            float mb = msk[kt + ks * 16 + r];
            #pragma unroll
            for (int i = 0; i < 4; ++i) s[ks][i] = fmaf(a[i], 0.125f, mb);
        }
        float alpha[4];
        #pragma unroll
        for (int i = 0; i < 4; ++i) {
            float t2 = fmaxf(fmaxf(s[0][i], s[1][i]), fmaxf(s[2][i], s[3][i]));
            t2 = fmaxf(t2, __shfl_xor(t2, 1));
            t2 = fmaxf(t2, __shfl_xor(t2, 2));
            t2 = fmaxf(t2, __shfl_xor(t2, 4));
            t2 = fmaxf(t2, __shfl_xor(t2, 8));
            float mn = fmaxf(m[i], t2);
            alpha[i] = __expf(m[i] - mn);
            m[i] = mn;
        }
        #pragma unroll
        for (int i = 0; i < 4; ++i) {
            float e0 = __expf(s[0][i] - m[i]);
            float e1 = __expf(s[1][i] - m[i]);
            float e2 = __expf(s[2][i] - m[i]);
            float e3 = __expf(s[3][i] - m[i]);
            s[0][i] = e0; s[1][i] = e1; s[2][i] = e2; s[3][i] = e3;
            float rs = (e0 + e1) + (e2 + e3);
            rs += __shfl_xor(rs, 1);
            rs += __shfl_xor(rs, 2);
            rs += __shfl_xor(rs, 4);
            rs += __shfl_xor(rs, 8);
            l[i] = l[i] * alpha[i] + rs;
        }
        #pragma unroll
        for (int nt = 0; nt < 4; ++nt)
            #pragma unroll
            for (int i = 0; i < 4; ++i) o[nt][i] *= alpha[i];
        #pragma unroll
        for (int ks = 0; ks < 4; ++ks) {
            int kc = ks * 2 + (r >> 3);
            #pragma unroll
            for (int i = 0; i < 4; ++i) {
                int mr = q * 4 + i;
                pw[mr * 64 + ((kc ^ (mr & 7)) * 8) + (r & 7)] = (bf16)s[ks][i];
            }
        }
        #pragma unroll
        for (int ks2 = 0; ks2 < 2; ++ks2) {
            int vpo = (((ks2 * 4 + q) ^ (r & 7)) * 8);
            bf16x8 pf = *reinterpret_cast<const bf16x8*>(&pw[r * 64 + vpo]);
            #pragma unroll
            for (int nt = 0; nt < 4; ++nt) {
                bf16x8 vf = *reinterpret_cast<const bf16x8*>(&Vb[(nt * 16 + r) * 64 + vpo]);
                o[nt] = __builtin_amdgcn_mfma_f32_16x16x32_bf16(pf, vf, o[nt], 0, 0, 0);
            }
        }
    }

    float inv[4];
    #pragma unroll
    for (int i = 0; i < 4; ++i) inv[i] = 1.0f / l[i];
    #pragma unroll
    for (int nt = 0; nt < 4; ++nt)
        #pragma unroll
        for (int i = 0; i < 4; ++i)
            out[(size_t)(b * 1024 + qb * 64 + w * 16 + q * 4 + i) * DM + h * 64 + nt * 16 + r] =
                (bf16)(o[nt][i] * inv[i]);
}

// ---------------------------------------------------------------------------
extern "C" void kernel_launch(void* const* d_in, const int* in_sizes, int n_in,
                              void* d_out, int out_size, void* d_ws, size_t ws_size,
                              hipStream_t stream) {
    const float* x      = (const float*)d_in[0];
    const int*   mask   = (const int*)  d_in[1];
    const float* w_q    = (const float*)d_in[2];
    const float* w_k    = (const float*)d_in[3];
    const float* w_v    = (const float*)d_in[4];
    const float* w_o    = (const float*)d_in[5];
    const float* alpha1 = (const float*)d_in[6];
    const float* beta1  = (const float*)d_in[7];
    const float* alpha2 = (const float*)d_in[8];
    const float* beta2  = (const float*)d_in[9];
    const float* fc1_w  = (const float*)d_in[10];
    const float* fc1_b  = (const float*)d_in[11];
    const float* fc2_w  = (const float*)d_in[12];
    const float* fc2_b  = (const float*)d_in[13];
    float* out = (float*)d_out;

    char* ws = (char*)d_ws;
    const size_t MB = 1024 * 1024;
    bf16*  wqkv_b = (bf16*)(ws +  0 * MB);   // 6 MB  (dead after QKV gemm)
    bf16*  wo_b   = (bf16*)(ws +  6 * MB);   // 2 MB  (dead after o-proj)
    bf16*  f1w_b  = (bf16*)(ws +  8 * MB);   // 8 MB  (dead after fc1)
    bf16*  f2w_b  = (bf16*)(ws + 16 * MB);   // 8 MB
    bf16*  xn     = (bf16*)(ws + 24 * MB);   // 4 MB
    bf16*  qkvb   = (bf16*)(ws + 28 * MB);   // 12 MB (dead after attn)
    bf16*  vtb    = (bf16*)(ws + 40 * MB);   // 4 MB  (dead after attn)
    bf16*  attnb  = (bf16*)(ws + 44 * MB);   // 4 MB  (dead after o-proj)
    float* x2     = (float*)(ws + 48 * MB);  // 8 MB
    float* po     = (float*)(ws + 28 * MB);  // 16 MB o-proj partials (over qkv/vt)
    bf16*  hb     = (bf16*)(ws + 28 * MB);   // 16 MB fc1 out (over po)
    float* pf2    = (float*)(ws +  0 * MB);  // 16 MB fc2 partials (over dead weights)

    // 1) weights -> bf16 + ln1, one dispatch
    prep_kernel<<<14336, 256, 0, stream>>>(
        (const float4*)w_q, (const float4*)w_k, (const float4*)w_v, (const float4*)w_o,
        (const float4*)fc1_w, (const float4*)fc2_w,
        (bf16x4*)wqkv_b, (bf16x4*)wo_b, (bf16x4*)f1w_b, (bf16x4*)f2w_b,
        x, alpha1, beta1, xn);

    // 2) fused QKV projection
    gemm128<0><<<dim3(QKVN / 128, NTOK / 128, 1), 256, 0, stream>>>(
        xn, wqkv_b, qkvb, nullptr, NTOK, QKVN, DM, DM);

    // 3) V -> (B,H,DK,S)
    transpose_v<<<dim3(32, 2, 32), dim3(32, 32), 0, stream>>>(qkvb, vtb);

    // 4) flash attention (512 blocks: 64 q-rows each)
    attn_kernel<<<512, 256, 0, stream>>>(qkvb, vtb, mask, attnb);

    // 5) o-proj split-K=2 partials
    gemm128<4><<<dim3(DM / 128, NTOK / 128, 2), 256, 0, stream>>>(
        attnb, wo_b, po, nullptr, NTOK, DM, DM, DM / 2);

    // 6) reduce + residual -> x2, fused ln2 -> xn
    reduce_ln_kernel<<<NTOK, 256, 0, stream>>>(po, x, alpha2, beta2, x2, xn);

    // 7) fc1 + bias + relu
    gemm128<1><<<dim3(DFC / 128, NTOK / 128, 1), 256, 0, stream>>>(
        xn, f1w_b, hb, fc1_b, NTOK, DFC, DM, DM);

    // 8) fc2 split-K=2 partials
    gemm128<4><<<dim3(DM / 128, NTOK / 128, 2), 256, 0, stream>>>(
        hb, f2w_b, pf2, nullptr, NTOK, DM, DFC, DFC / 2);

    // 9) reduce + bias + residual -> out
    reduce_out_kernel<<<2048, 256, 0, stream>>>(pf2, fc2_b, x2, out);
}